// Round 4
// baseline (260.525 us; speedup 1.0000x reference)
//
#include <hip/hip_runtime.h>
#include <hip/hip_fp16.h>
#include <math.h>

// Transformer-XL relative multi-head attention, MI355X. B=2,S=2048,D=512,H=8,dh=64.
// Round-16: attn_fused -> T3 2-phase pipeline (double-buffered K/V staging).
//   r15 post-mortem (confirmed): cooperative bulk staging fixed the serial-
//   latency stall (142->65.5us, MfmaUtil 4.8->10, VALU 18->39).  Residual
//   stall: stage(t+1) was issued AFTER compute(t), right before the barrier
//   that drains it -> full DMA flight exposed every tile.  Fix per the T3
//   recipe: issue STAGE_KV(t+1) at the TOP of tile t into the other buffer,
//   compute from the current buffer, re-issue the wave-private Pos window
//   mid-tile after lgkmcnt(0), ONE barrier per tile at the bottom (16
//   barriers removed).  K/V double-buffered: LDS = 32+32+16 = 80KB ->
//   exactly 2 blocks/CU (163840/81920).  DMA flies under compute.
//  1. conv_inputs : x,pos fp32 -> fp16.   2. conv_wt: 5 weights -> fp16 W^T.
//  3. proj_mfma   : QU(+u)/QV(+v), K, Pb [s][d]; VT [d][s]  (fp16 MFMA).
//  4. per head-chunk: pos_gemm -> Pshift fp16 ; attn_fused -> ctx fp16.
//  5. out_mfma    : out(fp32) = ctx @ Wo + bo.

#define S_LEN 2048
#define NH 8
#define DHD 64
#define DM 512
#define NBH 16
#define CHUNK_CAP 16
#define HEAD_ELEMS (S_LEN * DHD)
#define SS ((size_t)S_LEN * (size_t)S_LEN)

// workspace byte offsets
#define BY_QU  0u               // fp16 [16][2048][64]  4 MB
#define BY_QV  4194304u         // fp16 [16][2048][64]  4 MB
#define BY_K   8388608u         // fp16 [16][2048][64]  4 MB
#define BY_VT  12582912u        // fp16 [16][64][2048]  4 MB
#define BY_PB  16777216u        // fp16 [16][2048][64]  4 MB
#define BY_XH  20971520u        // fp16 [2][2048][512]  4 MB
#define BY_PH  25165824u        // fp16 [2][2048][512]  4 MB
#define BY_WT  29360128u        // fp16 [5][512][512] transposed, 2.62 MB
#define BY_CTX 31981568u        // fp16 [2][2048][512]  4 MB
#define BY_PP  36175872u        // fp16 [c][2048][2048] SHIFTED Ppos, 8.39 MB/head
#define PP_HEAD_BYTES 8388608u
#define WT_MAT_HALFS 262144u

typedef short v8s __attribute__((ext_vector_type(8)));
typedef float v4f __attribute__((ext_vector_type(4)));

static __device__ __forceinline__ unsigned short f2h(float f) {
    __half h = __float2half(f);
    return *reinterpret_cast<unsigned short*>(&h);
}
static __device__ __forceinline__ float h2f(unsigned short u) {
    __half h = *reinterpret_cast<__half*>(&u);
    return __half2float(h);
}
static __device__ __forceinline__ unsigned pkh(float a, float b) {
    return (unsigned)f2h(a) | ((unsigned)f2h(b) << 16);
}

// ---------------------------------------------------------------------------
// conv_inputs: fp32 -> fp16, 4 els/thread. z: 0 = x, 1 = pos.
// ---------------------------------------------------------------------------
__global__ __launch_bounds__(256)
void conv_inputs(const float* __restrict__ x, const float* __restrict__ pos,
                 char* __restrict__ wsb)
{
    const float* src = blockIdx.z ? pos : x;
    unsigned short* dst = (unsigned short*)(wsb + (blockIdx.z ? BY_PH : BY_XH));
    int i = (blockIdx.x * 256 + threadIdx.x) * 4;
    float4 a = *(const float4*)(src + i);
    ushort4 p;
    p.x = f2h(a.x); p.y = f2h(a.y); p.z = f2h(a.z); p.w = f2h(a.w);
    *(ushort4*)(dst + i) = p;
}

// ---------------------------------------------------------------------------
// conv_wt: WT[m][n][k] = W_m[k][n] fp16. 64x64 LDS tile transpose.
// ---------------------------------------------------------------------------
__global__ __launch_bounds__(256)
void conv_wt(const float* __restrict__ Wq, const float* __restrict__ Wk,
             const float* __restrict__ Wv, const float* __restrict__ Wp,
             const float* __restrict__ Wo, char* __restrict__ wsb)
{
    __shared__ float T[64][65];
    const float* W = (blockIdx.z == 0) ? Wq : (blockIdx.z == 1) ? Wk :
                     (blockIdx.z == 2) ? Wv : (blockIdx.z == 3) ? Wp : Wo;
    unsigned short* WT = (unsigned short*)(wsb + BY_WT) + blockIdx.z * WT_MAT_HALFS;
    const int n0 = blockIdx.x * 64, k0 = blockIdx.y * 64;
    const int t = threadIdx.x;
#pragma unroll
    for (int i = 0; i < 4; ++i) {
        int f = t + i * 256;
        int row = f >> 4, c4 = f & 15;
        *(float4*)&T[row][c4 * 4] = *(const float4*)(W + (size_t)(k0 + row) * 512 + n0 + c4 * 4);
    }
    __syncthreads();
#pragma unroll
    for (int i = 0; i < 4; ++i) {
        int f = t + i * 256;
        int n = f >> 4, k4 = f & 15;
        ushort4 p;
        p.x = f2h(T[k4 * 4 + 0][n]); p.y = f2h(T[k4 * 4 + 1][n]);
        p.z = f2h(T[k4 * 4 + 2][n]); p.w = f2h(T[k4 * 4 + 3][n]);
        *(ushort4*)(WT + (size_t)(n0 + n) * 512 + k0 + k4 * 4) = p;
    }
}

// ---------------------------------------------------------------------------
// proj_mfma: all four projections via fp16 MFMA, no LDS, 4 waves = 2x2 64x64.
// modes 0(Q),1(K),3(P): SWAPPED C[d][s]; mode 2(V): C[s][d] -> VT store.
// ---------------------------------------------------------------------------
__global__ __launch_bounds__(256)
void proj_mfma(const float* __restrict__ bq, const float* __restrict__ bk,
               const float* __restrict__ bvp,
               const float* __restrict__ uvec, const float* __restrict__ vvec,
               char* __restrict__ wsb)
{
    const int t = threadIdx.x;
    const int wave = t >> 6, lane = t & 63;
    const int quad = lane >> 4, l16 = lane & 15;
    const int wm = wave >> 1, wn = wave & 1;
    const int mode = blockIdx.z;
    const unsigned short* xh = (const unsigned short*)(wsb + BY_XH);
    const unsigned short* ph = (const unsigned short*)(wsb + BY_PH);
    const unsigned short* wt = (const unsigned short*)(wsb + BY_WT);

    v4f acc[4][4];
#pragma unroll
    for (int i = 0; i < 4; ++i)
#pragma unroll
        for (int j = 0; j < 4; ++j) acc[i][j] = (v4f){0.f, 0.f, 0.f, 0.f};

    if (mode != 2) {
        const int d0 = blockIdx.y * 128 + wm * 64;
        const int s0 = blockIdx.x * 128 + wn * 64;
        const int mat = (mode == 0) ? 0 : (mode == 1) ? 1 : 3;
        const unsigned short* A = wt + (size_t)mat * WT_MAT_HALFS;   // [d][k]
        const unsigned short* B = (mode == 3) ? ph : xh;             // [s][k]

        for (int kk = 0; kk < 16; ++kk) {
            v8s af[4], bf[4];
#pragma unroll
            for (int i = 0; i < 4; ++i) {
                af[i] = *(const v8s*)(A + (size_t)(d0 + i * 16 + l16) * 512 + kk * 32 + quad * 8);
                bf[i] = *(const v8s*)(B + (size_t)(s0 + i * 16 + l16) * 512 + kk * 32 + quad * 8);
            }
#pragma unroll
            for (int i = 0; i < 4; ++i)
#pragma unroll
                for (int j = 0; j < 4; ++j)
                    acc[i][j] = __builtin_amdgcn_mfma_f32_16x16x32_f16(af[i], bf[j], acc[i][j], 0, 0, 0);
        }

#pragma unroll
        for (int i = 0; i < 4; ++i) {
            int db = d0 + i * 16 + quad * 4;
            int h = db >> 6, dl = db & 63;
            float4 b4 = (mode == 3) ? make_float4(0.f, 0.f, 0.f, 0.f)
                        : (mode == 0) ? *(const float4*)(bq + db)
                                      : *(const float4*)(bk + db);
#pragma unroll
            for (int j = 0; j < 4; ++j) {
                int s = s0 + j * 16 + l16;
                int bb = s >> 11, srow = s & 2047;
                size_t o = ((size_t)(bb * NH + h) * S_LEN + srow) * DHD + dl;
                if (mode == 0) {
                    float4 u4 = *(const float4*)(uvec + db);
                    float4 v4 = *(const float4*)(vvec + db);
                    unsigned short* qu = (unsigned short*)(wsb + BY_QU);
                    unsigned short* qv = (unsigned short*)(wsb + BY_QV);
                    ushort4 pu, pv;
                    pu.x = f2h(acc[i][j][0] + b4.x + u4.x);
                    pu.y = f2h(acc[i][j][1] + b4.y + u4.y);
                    pu.z = f2h(acc[i][j][2] + b4.z + u4.z);
                    pu.w = f2h(acc[i][j][3] + b4.w + u4.w);
                    pv.x = f2h(acc[i][j][0] + b4.x + v4.x);
                    pv.y = f2h(acc[i][j][1] + b4.y + v4.y);
                    pv.z = f2h(acc[i][j][2] + b4.z + v4.z);
                    pv.w = f2h(acc[i][j][3] + b4.w + v4.w);
                    *(ushort4*)(qu + o) = pu;
                    *(ushort4*)(qv + o) = pv;
                } else {
                    unsigned short* dst = (unsigned short*)(wsb + (mode == 1 ? BY_K : BY_PB));
                    ushort4 pk;
                    pk.x = f2h(acc[i][j][0] + b4.x);
                    pk.y = f2h(acc[i][j][1] + b4.y);
                    pk.z = f2h(acc[i][j][2] + b4.z);
                    pk.w = f2h(acc[i][j][3] + b4.w);
                    *(ushort4*)(dst + o) = pk;
                }
            }
        }
    } else {
        const int s0 = blockIdx.x * 128 + wm * 64;
        const int d0 = blockIdx.y * 128 + wn * 64;
        const unsigned short* A = xh;                                 // [s][k]
        const unsigned short* B = wt + (size_t)2 * WT_MAT_HALFS;      // [d][k]

        for (int kk = 0; kk < 16; ++kk) {
            v8s af[4], bf[4];
#pragma unroll
            for (int i = 0; i < 4; ++i) {
                af[i] = *(const v8s*)(A + (size_t)(s0 + i * 16 + l16) * 512 + kk * 32 + quad * 8);
                bf[i] = *(const v8s*)(B + (size_t)(d0 + i * 16 + l16) * 512 + kk * 32 + quad * 8);
            }
#pragma unroll
            for (int i = 0; i < 4; ++i)
#pragma unroll
                for (int j = 0; j < 4; ++j)
                    acc[i][j] = __builtin_amdgcn_mfma_f32_16x16x32_f16(af[i], bf[j], acc[i][j], 0, 0, 0);
        }

        unsigned short* vt = (unsigned short*)(wsb + BY_VT);
#pragma unroll
        for (int j = 0; j < 4; ++j) {
            int d = d0 + j * 16 + l16;
            int h = d >> 6, dl = d & 63;
            float bval = bvp[d];
#pragma unroll
            for (int i = 0; i < 4; ++i) {
                int sb = s0 + i * 16 + quad * 4;
                int bb = sb >> 11, srow = sb & 2047;
                size_t o = ((size_t)(bb * NH + h) * DHD + dl) * S_LEN + srow;
                ushort4 pk;
                pk.x = f2h(acc[i][j][0] + bval);
                pk.y = f2h(acc[i][j][1] + bval);
                pk.z = f2h(acc[i][j][2] + bval);
                pk.w = f2h(acc[i][j][3] + bval);
                *(ushort4*)(vt + o) = pk;
            }
        }
    }
}

// ---------------------------------------------------------------------------
// pos GEMM -> SHIFTED store (unchanged from Round-14, verified).
// ---------------------------------------------------------------------------
__global__ __launch_bounds__(256)
void pos_gemm(const unsigned short* __restrict__ qv,
              const unsigned short* __restrict__ pb,
              unsigned short* __restrict__ pp, int head_base)
{
    __shared__ unsigned short T[128][132];   // [q_local][j_local], pad->no conflicts
    const int t = threadIdx.x;
    const int wave = t >> 6, lane = t & 63;
    const int quad = lane >> 4, l16 = lane & 15;
    const int wm = wave >> 1, wn = wave & 1;
    const int z = blockIdx.z, g = head_base + z;
    const int m0 = blockIdx.y * 128;             // j-block base
    const int n0 = blockIdx.x * 128;             // q-block base
    const int m0w = m0 + wm * 64;                // wave j-subtile
    const int n0w = n0 + wn * 64;                // wave q-subtile

    const unsigned short* A = pb + (size_t)g * HEAD_ELEMS;   // [j][d]
    const unsigned short* B = qv + (size_t)g * HEAD_ELEMS;   // [q][d]
    unsigned short* out = pp + (size_t)z * SS;               // Pshift [q][k]

    v8s af[4][2], bf[4][2];
#pragma unroll
    for (int i = 0; i < 4; ++i)
#pragma unroll
        for (int kk = 0; kk < 2; ++kk) {
            af[i][kk] = *(const v8s*)(A + (size_t)(m0w + i * 16 + l16) * DHD + kk * 32 + quad * 8);
            bf[i][kk] = *(const v8s*)(B + (size_t)(n0w + i * 16 + l16) * DHD + kk * 32 + quad * 8);
        }

#pragma unroll
    for (int i = 0; i < 4; ++i)
#pragma unroll
        for (int j = 0; j < 4; ++j) {
            v4f c = (v4f){0.f, 0.f, 0.f, 0.f};
            c = __builtin_amdgcn_mfma_f32_16x16x32_f16(af[i][0], bf[j][0], c, 0, 0, 0);
            c = __builtin_amdgcn_mfma_f32_16x16x32_f16(af[i][1], bf[j][1], c, 0, 0, 0);
            int jl = wm * 64 + i * 16 + quad * 4;    // j_local (mult of 4)
            int ql = wn * 64 + j * 16 + l16;         // q_local
            ushort4 pk;
            pk.x = f2h(c[0]); pk.y = f2h(c[1]); pk.z = f2h(c[2]); pk.w = f2h(c[3]);
            *(ushort4*)&T[ql][jl] = pk;              // 8B-aligned (stride 264B)
        }

    __syncthreads();

#pragma unroll 4
    for (int m = 0; m < 32; ++m) {
        int ql = wave * 32 + m;
        int q = n0 + ql;
        int jm = 2047 - q - m0;   // j_local < jm -> row q-1 branch
#pragma unroll
        for (int e = 0; e < 2; ++e) {
            int jl = lane + e * 64;
            unsigned short hv = T[ql][jl];
            if (jl < jm) {
                if (q > 0)
                    out[(size_t)(q - 1) * S_LEN + (m0 + jl + q + 1)] = hv;
            } else {
                out[(size_t)q * S_LEN + (m0 + jl - 2047 + q)] = hv;
            }
        }
    }
}

// ---------------------------------------------------------------------------
// Flash attention, Round-16: q-split + T3 2-phase double-buffered staging.
// Block = 64 q-rows (4 waves x 16); k-tiles 0..15 (128 k each).
// Per tile t:
//   [top]    issue STAGE_KV(t+1) into buf (cur^1)   (8 global_load_lds)
//   compute  QK^T from Kbuf[cur] (swizzled ds_read), pos extract from PosB
//   [mid]    lgkmcnt(0); issue STAGE_POS(t+1) into PosB (wave-private,
//            own extraction reads retired -> safe to overwrite)
//   compute  softmax, P-pack, PV from Vbuf[cur]
//   [bottom] __syncthreads()  (compiler drains vmcnt -> stage t+1 complete;
//            also publishes: all waves done reading buf cur)
//   cur ^= 1
// DMA for t+1 flies under tile t's compute; ONE barrier per tile.
// LDS: K 2x16KB + V 2x16KB + Pos 16KB = 80 KB -> exactly 2 blocks/CU.
// ---------------------------------------------------------------------------
__global__ __launch_bounds__(256, 2)
void attn_fused(const unsigned short* __restrict__ qu,
                const unsigned short* __restrict__ kdat,
                const unsigned short* __restrict__ vtg,
                const unsigned short* __restrict__ pp,
                unsigned short* __restrict__ ctx, int head_base)
{
    __shared__ __align__(16) unsigned short Kbuf[2][8192];  // 2 x 16 KB
    __shared__ __align__(16) unsigned short Vbuf[2][8192];  // 2 x 16 KB
    __shared__ __align__(16) unsigned short PosB[4][2048];  // 4 KB/wave

    const int t = threadIdx.x;
    const int wave = t >> 6, lane = t & 63;
    const int quad = lane >> 4, l16 = lane & 15;
    const int z = blockIdx.x >> 5, qt = blockIdx.x & 31;
    const int g = head_base + z;
    const int q0w = qt * 64 + wave * 16;     // this wave's q-row base
    const int q = q0w + l16;                 // this lane's q row

    const unsigned short* QU = qu   + (size_t)g * HEAD_ELEMS;
    const unsigned short* Kg = kdat + (size_t)g * HEAD_ELEMS;
    const unsigned short* Vg = vtg  + (size_t)g * HEAD_ELEMS;
    const unsigned short* Pg = pp   + (size_t)z * SS;
    unsigned short* pbuf = &PosB[wave][0];
    const unsigned short* gdma = Pg + (size_t)q * S_LEN;    // row base, 4KB-aligned

    // staging lane roles (constant per thread)
    const int krow_l = lane >> 3, kch_l = lane & 7;    // within 8-row K group
    const int vrow_l = lane >> 4, vch_l = lane & 15;   // within 4-row V group

#define STAGE_KV(TT, CUR)                                                     \
    {                                                                         \
        const int k0s = (TT) * 128;                                           \
        unsigned short* kb = &Kbuf[CUR][0];                                   \
        unsigned short* vb = &Vbuf[CUR][0];                                   \
        _Pragma("unroll")                                                     \
        for (int jj = 0; jj < 4; ++jj) {                                      \
            const int j = wave * 4 + jj;                                      \
            {                                                                 \
                int kr = j * 8 + krow_l;                                      \
                int kc = kch_l ^ (kr & 7);                                    \
                __builtin_amdgcn_global_load_lds(                             \
                    (const __attribute__((address_space(1))) unsigned int*)   \
                        (Kg + (size_t)(k0s + kr) * DHD + kc * 8),             \
                    (__attribute__((address_space(3))) unsigned int*)         \
                        (kb + j * 512), 16, 0, 0);                            \
            }                                                                 \
            {                                                                 \
                int vr = j * 4 + vrow_l;                                      \
                int vc = vch_l ^ (vr & 15);                                   \
                __builtin_amdgcn_global_load_lds(                             \
                    (const __attribute__((address_space(1))) unsigned int*)   \
                        (Vg + (size_t)vr * S_LEN + k0s + vc * 8),             \
                    (__attribute__((address_space(3))) unsigned int*)         \
                        (vb + j * 512), 16, 0, 0);                            \
            }                                                                 \
        }                                                                     \
    }

#define STAGE_POS(TT)                                                         \
    {                                                                         \
        const int k0s = (TT) * 128;                                           \
        _Pragma("unroll")                                                     \
        for (int jj = 0; jj < 4; ++jj)                                        \
            __builtin_amdgcn_global_load_lds(                                 \
                (const __attribute__((address_space(1))) unsigned int*)       \
                    (gdma + k0s + (jj * 4 + quad) * 8),                       \
                (__attribute__((address_space(3))) unsigned int*)             \
                    (pbuf + jj * 512), 16, 0, 0);                             \
    }

    // prologue: stage tile 0, drain, enter loop
    STAGE_KV(0, 0)
    STAGE_POS(0)

    const v8s bq0 = *(const v8s*)(QU + (size_t)q * DHD + quad * 8);
    const v8s bq1 = *(const v8s*)(QU + (size_t)q * DHD + 32 + quad * 8);

    float m_run = -1e30f, l_run = 0.f;
    v4f accv[4];
#pragma unroll
    for (int r = 0; r < 4; ++r) accv[r] = (v4f){0.f, 0.f, 0.f, 0.f};
    const float scale = 0.04419417382415922f;

    __syncthreads();   // stage(0) complete & visible

    int cur = 0;
    for (int tt = 0; tt < 16; ++tt) {
        const int k0 = tt * 128;

        // issue next tile's K/V DMA into the other buffer (flies under compute)
        if (tt < 15) STAGE_KV(tt + 1, cur ^ 1)

        // QK^T from Kbuf[cur] (swizzled ds_read_b128)
        v4f sacc[8];
#pragma unroll
        for (int nt = 0; nt < 8; ++nt) {
            int r = nt * 16 + l16;
            const unsigned short* kl = &Kbuf[cur][0] + r * 64;
            v8s a0 = *(const v8s*)(kl + ((quad ^ (r & 7)) * 8));
            v8s a1 = *(const v8s*)(kl + (((4 + quad) ^ (r & 7)) * 8));
            v4f c = (v4f){0.f, 0.f, 0.f, 0.f};
            c = __builtin_amdgcn_mfma_f32_16x16x32_f16(a0, bq0, c, 0, 0, 0);
            c = __builtin_amdgcn_mfma_f32_16x16x32_f16(a1, bq1, c, 0, 0, 0);
            sacc[nt] = c;
        }

        // add pre-shifted pos from PosB + scale
        float tm = -1e30f;
#pragma unroll
        for (int nt = 0; nt < 8; ++nt) {
            int kb = k0 + nt * 16 + quad * 4;
            int cc = nt * 2 + (quad >> 1);
            uint2 w = *(const uint2*)((const char*)pbuf +
                         (cc >> 2) * 1024 + (cc & 3) * 256 + l16 * 16 + (quad & 1) * 8);
            unsigned short h_[4] = { (unsigned short)(w.x & 0xffff),
                                     (unsigned short)(w.x >> 16),
                                     (unsigned short)(w.y & 0xffff),
                                     (unsigned short)(w.y >> 16) };
#pragma unroll
            for (int reg = 0; reg < 4; ++reg) {
                int k = kb + reg;
                float pv = (k == q + 1) ? 0.f : h2f(h_[reg]);
                sacc[nt][reg] = (sacc[nt][reg] + pv) * scale;
                tm = fmaxf(tm, sacc[nt][reg]);
            }
        }

        // wave's extraction + QK ds_reads retired -> safe to refill PosB
        __builtin_amdgcn_s_waitcnt(0xc07f);   // lgkmcnt(0)
        if (tt < 15) STAGE_POS(tt + 1)

        // online softmax (per-lane q = l16; reduce across the 4 quads)
        tm = fmaxf(tm, __shfl_xor(tm, 16));
        tm = fmaxf(tm, __shfl_xor(tm, 32));
        float mn = fmaxf(m_run, tm);
        float al = __expf(m_run - mn);
        float rs = 0.f;
#pragma unroll
        for (int nt = 0; nt < 8; ++nt)
#pragma unroll
            for (int reg = 0; reg < 4; ++reg) {
                sacc[nt][reg] = __expf(sacc[nt][reg] - mn);
                rs += sacc[nt][reg];
            }
        rs += __shfl_xor(rs, 16);
        rs += __shfl_xor(rs, 32);
        l_run = l_run * al + rs;
        m_run = mn;

        float alr[4];
#pragma unroll
        for (int reg = 0; reg < 4; ++reg) alr[reg] = __shfl(al, quad * 4 + reg);
#pragma unroll
        for (int ntd = 0; ntd < 4; ++ntd)
#pragma unroll
            for (int reg = 0; reg < 4; ++reg) accv[ntd][reg] *= alr[reg];

        // pack P to fp16 word-pairs (per nt): pk[nt][0] = regs 0,1; [1] = 2,3
        unsigned pk[8][2];
#pragma unroll
        for (int nt = 0; nt < 8; ++nt) {
            pk[nt][0] = pkh(sacc[nt][0], sacc[nt][1]);
            pk[nt][1] = pkh(sacc[nt][2], sacc[nt][3]);
        }

        // PV: A-fragment via shfl transpose, B from Vbuf[cur] (swizzled)
        const int sA = l16 + ((quad & 1) * 32);
        const bool hi = (quad >= 2);
#pragma unroll
        for (int c4 = 0; c4 < 4; ++c4) {
            unsigned a0A = __shfl((int)pk[c4 * 2][0], sA);
            unsigned a1A = __shfl((int)pk[c4 * 2][1], sA);
            unsigned a0B = __shfl((int)pk[c4 * 2][0], sA + 16);
            unsigned a1B = __shfl((int)pk[c4 * 2][1], sA + 16);
            unsigned b0A = __shfl((int)pk[c4 * 2 + 1][0], sA);
            unsigned b1A = __shfl((int)pk[c4 * 2 + 1][1], sA);
            unsigned b0B = __shfl((int)pk[c4 * 2 + 1][0], sA + 16);
            unsigned b1B = __shfl((int)pk[c4 * 2 + 1][1], sA + 16);
            union { unsigned u[4]; v8s v; } apu;
            apu.u[0] = hi ? b0A : a0A;
            apu.u[1] = hi ? b1A : a1A;
            apu.u[2] = hi ? b0B : a0B;
            apu.u[3] = hi ? b1B : a1B;
#pragma unroll
            for (int ntd = 0; ntd < 4; ++ntd) {
                int d = ntd * 16 + l16;
                v8s bv8 = *(const v8s*)(&Vbuf[cur][0] + d * 128 +
                                        (((c4 * 4 + quad) ^ (d & 15)) * 8));
                accv[ntd] = __builtin_amdgcn_mfma_f32_16x16x32_f16(apu.v, bv8, accv[ntd], 0, 0, 0);
            }
        }

        __syncthreads();   // drains stage(t+1) DMA; publishes buffers; frees cur
        cur ^= 1;
    }
#undef STAGE_KV
#undef STAGE_POS

    // epilogue: each wave owns its 16 q-rows completely.
    // accv[ntd][reg] = out[q = q0w + quad*4+reg][d = ntd*16 + l16] (unnormalized)
    const int bb = g >> 3, h = g & 7;
    float inv[4];
#pragma unroll
    for (int reg = 0; reg < 4; ++reg)
        inv[reg] = 1.f / __shfl(l_run, quad * 4 + reg);
#pragma unroll
    for (int ntd = 0; ntd < 4; ++ntd)
#pragma unroll
        for (int reg = 0; reg < 4; ++reg) {
            int qq = q0w + quad * 4 + reg;
            ctx[((size_t)(bb * S_LEN + qq)) * DM + h * DHD + ntd * 16 + l16] =
                f2h(accv[ntd][reg] * inv[reg]);
        }
}

// ---------------------------------------------------------------------------
// out_mfma: out(fp32)[s][n] = ctx(fp16) @ Wo + bo.  SWAPPED: C[n][s] ->
// float4 stores.  grid (32, 4): x = s-tile(128), y = n-tile(128).
// ---------------------------------------------------------------------------
__global__ __launch_bounds__(256)
void out_mfma(const float* __restrict__ bo, const char* __restrict__ wsb,
              float* __restrict__ out)
{
    const int t = threadIdx.x;
    const int wave = t >> 6, lane = t & 63;
    const int quad = lane >> 4, l16 = lane & 15;
    const int wm = wave >> 1, wn = wave & 1;
    const int n0 = blockIdx.y * 128 + wm * 64;
    const int s0 = blockIdx.x * 128 + wn * 64;
    const unsigned short* A = (const unsigned short*)(wsb + BY_WT) + (size_t)4 * WT_MAT_HALFS;
    const unsigned short* B = (const unsigned short*)(wsb + BY_CTX);

    v4f acc[4][4];
#pragma unroll
    for (int i = 0; i < 4; ++i)
#pragma unroll
        for (int j = 0; j < 4; ++j) acc[i][j] = (v4f){0.f, 0.f, 0.f, 0.f};

    for (int kk = 0; kk < 16; ++kk) {
        v8s af[4], bf[4];
#pragma unroll
        for (int i = 0; i < 4; ++i) {
            af[i] = *(const v8s*)(A + (size_t)(n0 + i * 16 + l16) * 512 + kk * 32 + quad * 8);
            bf[i] = *(const v8s*)(B + (size_t)(s0 + i * 16 + l16) * 512 + kk * 32 + quad * 8);
        }
#pragma unroll
        for (int i = 0; i < 4; ++i)
#pragma unroll
            for (int j = 0; j < 4; ++j)
                acc[i][j] = __builtin_amdgcn_mfma_f32_16x16x32_f16(af[i], bf[j], acc[i][j], 0, 0, 0);
    }

#pragma unroll
    for (int i = 0; i < 4; ++i) {
        int nb = n0 + i * 16 + quad * 4;
        float4 b4 = *(const float4*)(bo + nb);
#pragma unroll
        for (int j = 0; j < 4; ++j) {
            int s = s0 + j * 16 + l16;
            *(float4*)(out + (size_t)s * DM + nb) =
                make_float4(acc[i][j][0] + b4.x, acc[i][j][1] + b4.y,
                            acc[i][j][2] + b4.z, acc[i][j][3] + b4.w);
        }
    }
}

// Fallback when ws_size is insufficient: clean mismatch instead of OOB writes.
__global__ void zero_fill(float* __restrict__ p, int n)
{
    int i = blockIdx.x * 256 + threadIdx.x;
    if (i < n) p[i] = 0.f;
}

// ---------------------------------------------------------------------------
extern "C" void kernel_launch(void* const* d_in, const int* in_sizes, int n_in,
                              void* d_out, int out_size, void* d_ws, size_t ws_size,
                              hipStream_t stream)
{
    const float* x   = (const float*)d_in[0];
    const float* pos = (const float*)d_in[1];
    const float* Wq  = (const float*)d_in[2];
    const float* bq  = (const float*)d_in[3];
    const float* Wk  = (const float*)d_in[4];
    const float* bk  = (const float*)d_in[5];
    const float* Wv  = (const float*)d_in[6];
    const float* bv  = (const float*)d_in[7];
    const float* Wp  = (const float*)d_in[8];
    const float* u   = (const float*)d_in[9];
    const float* v   = (const float*)d_in[10];
    const float* Wo  = (const float*)d_in[11];
    const float* bo  = (const float*)d_in[12];
    char* wsb  = (char*)d_ws;
    float* out = (float*)d_out;

    // Workspace guard: need BY_PP + >=1 head of Pshift + slack.
    if (ws_size < (size_t)BY_PP + PP_HEAD_BYTES + 4096) {
        zero_fill<<<(out_size + 255) / 256, 256, 0, stream>>>(out, out_size);
        return;
    }

    // 1. dtype prep
    conv_inputs<<<dim3(2048, 1, 2), 256, 0, stream>>>(x, pos, wsb);
    conv_wt<<<dim3(8, 8, 5), 256, 0, stream>>>(Wq, Wk, Wv, Wp, Wo, wsb);

    // 2. projections (fp16 MFMA)
    proj_mfma<<<dim3(32, 4, 4), 256, 0, stream>>>(bq, bk, bv, u, v, wsb);

    // 3. attention in head-chunks sized to workspace.
    int c = (int)((ws_size - 4096 - (size_t)BY_PP) / (size_t)PP_HEAD_BYTES);
    if (c < 1) c = 1;
    if (c > CHUNK_CAP) c = CHUNK_CAP;

    for (int g0 = 0; g0 < NBH; g0 += c) {
        int cc = (NBH - g0 < c) ? (NBH - g0) : c;
        pos_gemm<<<dim3(16, 16, cc), 256, 0, stream>>>(
            (const unsigned short*)(wsb + BY_QV),
            (const unsigned short*)(wsb + BY_PB),
            (unsigned short*)(wsb + BY_PP), g0);
        attn_fused<<<dim3(cc * 32), 256, 0, stream>>>(
            (const unsigned short*)(wsb + BY_QU),
            (const unsigned short*)(wsb + BY_K),
            (const unsigned short*)(wsb + BY_VT),
            (const unsigned short*)(wsb + BY_PP),
            (unsigned short*)(wsb + BY_CTX), g0);
    }

    // 4. output projection (fp16 MFMA, fp32 out)
    out_mfma<<<dim3(32, 4), 256, 0, stream>>>(bo, wsb, out);
}

// Round 5
// 229.862 us; speedup vs baseline: 1.1334x; 1.1334x over previous
//
#include <hip/hip_runtime.h>
#include <hip/hip_fp16.h>
#include <math.h>

// Transformer-XL relative multi-head attention, MI355X. B=2,S=2048,D=512,H=8,dh=64.
// Round-17: FUSED pos-GEMM -> Ppos tensor eliminated.
//   r16 post-mortem: double-buffered staging REGRESSED (65.5->69.2us) -> DMA
//   flight was already hidden by 8-wave TLP; reverted.  Decomposition shows
//   attn is only ~27% of the 260us budget; the Ppos materialization round
//   trip (pos_gemm writes 134MB, attn re-fetches ~100MB = its FETCH_SIZE)
//   is the largest structural cost.  Fix: fuse.  Math:
//     Pshift[q][k] = qv[q]  . pb[2047+k-q]  (k <= q)
//                  = qv[q+1]. pb[k-q-2]     (k >= q+2),   0 at k = q+1.
//   Per (64-q-block x 128-k tile) the needed pb rows are ONE contiguous
//   <=192-row window (two windows only on the diagonal tile t_mix).  Each
//   block computes G = pb-window x qv on the fly (MFMA; A-op = pb from
//   global/L2, B-op = qv in 10 resident VGPR fragments), stores G into an
//   80x204 fp16 LDS tile (b32-pair stores, conflict-free 408B row stride),
//   extracts P with aligned uint2 + alignbit funnel (per-lane const phase).
//   scale folded into QU/QV at proj_mfma (no per-element mul in attn).
//   pos_gemm kernel, PosB, BY_PP workspace and the chunk loop are DELETED.
//  1. conv_inputs : x,pos fp32 -> fp16.   2. conv_wt: 5 weights -> fp16 W^T.
//  3. proj_mfma   : QU(+u)/QV(+v) PRESCALED, K, Pb [s][d]; VT [d][s].
//  4. attn_fused  : single dispatch, 16 heads x 32 q-blocks.
//  5. out_mfma    : out(fp32) = ctx @ Wo + bo.

#define S_LEN 2048
#define NH 8
#define DHD 64
#define DM 512
#define NBH 16
#define HEAD_ELEMS (S_LEN * DHD)

// workspace byte offsets
#define BY_QU  0u               // fp16 [16][2048][64]  4 MB  (prescaled q+u)
#define BY_QV  4194304u         // fp16 [16][2048][64]  4 MB  (prescaled q+v)
#define BY_K   8388608u         // fp16 [16][2048][64]  4 MB
#define BY_VT  12582912u        // fp16 [16][64][2048]  4 MB
#define BY_PB  16777216u        // fp16 [16][2048][64]  4 MB
#define BY_XH  20971520u        // fp16 [2][2048][512]  4 MB
#define BY_PH  25165824u        // fp16 [2][2048][512]  4 MB
#define BY_WT  29360128u        // fp16 [5][512][512] transposed, 2.62 MB
#define BY_CTX 31981568u        // fp16 [2][2048][512]  4 MB
#define BY_END 36175872u        // end of used workspace
#define WT_MAT_HALFS 262144u

#define GJP 204                 // G row pitch in halfs (408 B; 102 dw = 6 banks)

typedef short v8s __attribute__((ext_vector_type(8)));
typedef float v4f __attribute__((ext_vector_type(4)));

static __device__ __forceinline__ unsigned short f2h(float f) {
    __half h = __float2half(f);
    return *reinterpret_cast<unsigned short*>(&h);
}
static __device__ __forceinline__ float h2f(unsigned short u) {
    __half h = *reinterpret_cast<__half*>(&u);
    return __half2float(h);
}
static __device__ __forceinline__ unsigned pkh(float a, float b) {
    return (unsigned)f2h(a) | ((unsigned)f2h(b) << 16);
}

// read 4 halfs at offset p..p+3 from the 8-half aligned window starting at
// col c0 (c0 % 4 == 0) of LDS row `grow`.  p in 0..3, per-lane constant.
static __device__ __forceinline__ void g_read4(const unsigned short* grow,
                                               int c0, int p,
                                               unsigned short h[4])
{
    uint2 w0 = *(const uint2*)(grow + c0);
    uint2 w1 = *(const uint2*)(grow + c0 + 4);
    unsigned y0 = (p & 2) ? w0.y : w0.x;
    unsigned y1 = (p & 2) ? w1.x : w0.y;
    unsigned y2 = (p & 2) ? w1.y : w1.x;
    unsigned s = (unsigned)(p & 1) * 16u;
    unsigned v01 = __builtin_amdgcn_alignbit(y1, y0, s);
    unsigned v23 = __builtin_amdgcn_alignbit(y2, y1, s);
    h[0] = (unsigned short)(v01 & 0xffff);
    h[1] = (unsigned short)(v01 >> 16);
    h[2] = (unsigned short)(v23 & 0xffff);
    h[3] = (unsigned short)(v23 >> 16);
}

// ---------------------------------------------------------------------------
// conv_inputs: fp32 -> fp16, 4 els/thread. z: 0 = x, 1 = pos.
// ---------------------------------------------------------------------------
__global__ __launch_bounds__(256)
void conv_inputs(const float* __restrict__ x, const float* __restrict__ pos,
                 char* __restrict__ wsb)
{
    const float* src = blockIdx.z ? pos : x;
    unsigned short* dst = (unsigned short*)(wsb + (blockIdx.z ? BY_PH : BY_XH));
    int i = (blockIdx.x * 256 + threadIdx.x) * 4;
    float4 a = *(const float4*)(src + i);
    ushort4 p;
    p.x = f2h(a.x); p.y = f2h(a.y); p.z = f2h(a.z); p.w = f2h(a.w);
    *(ushort4*)(dst + i) = p;
}

// ---------------------------------------------------------------------------
// conv_wt: WT[m][n][k] = W_m[k][n] fp16. 64x64 LDS tile transpose.
// ---------------------------------------------------------------------------
__global__ __launch_bounds__(256)
void conv_wt(const float* __restrict__ Wq, const float* __restrict__ Wk,
             const float* __restrict__ Wv, const float* __restrict__ Wp,
             const float* __restrict__ Wo, char* __restrict__ wsb)
{
    __shared__ float T[64][65];
    const float* W = (blockIdx.z == 0) ? Wq : (blockIdx.z == 1) ? Wk :
                     (blockIdx.z == 2) ? Wv : (blockIdx.z == 3) ? Wp : Wo;
    unsigned short* WT = (unsigned short*)(wsb + BY_WT) + blockIdx.z * WT_MAT_HALFS;
    const int n0 = blockIdx.x * 64, k0 = blockIdx.y * 64;
    const int t = threadIdx.x;
#pragma unroll
    for (int i = 0; i < 4; ++i) {
        int f = t + i * 256;
        int row = f >> 4, c4 = f & 15;
        *(float4*)&T[row][c4 * 4] = *(const float4*)(W + (size_t)(k0 + row) * 512 + n0 + c4 * 4);
    }
    __syncthreads();
#pragma unroll
    for (int i = 0; i < 4; ++i) {
        int f = t + i * 256;
        int n = f >> 4, k4 = f & 15;
        ushort4 p;
        p.x = f2h(T[k4 * 4 + 0][n]); p.y = f2h(T[k4 * 4 + 1][n]);
        p.z = f2h(T[k4 * 4 + 2][n]); p.w = f2h(T[k4 * 4 + 3][n]);
        *(ushort4*)(WT + (size_t)(n0 + n) * 512 + k0 + k4 * 4) = p;
    }
}

// ---------------------------------------------------------------------------
// proj_mfma: all four projections via fp16 MFMA, no LDS, 4 waves = 2x2 64x64.
// modes 0(Q),1(K),3(P): SWAPPED C[d][s]; mode 2(V): C[s][d] -> VT store.
// Round-17: mode-0 outputs (QU, QV) are PRESCALED by 1/sqrt(D_MODEL).
// ---------------------------------------------------------------------------
__global__ __launch_bounds__(256)
void proj_mfma(const float* __restrict__ bq, const float* __restrict__ bk,
               const float* __restrict__ bvp,
               const float* __restrict__ uvec, const float* __restrict__ vvec,
               char* __restrict__ wsb)
{
    const int t = threadIdx.x;
    const int wave = t >> 6, lane = t & 63;
    const int quad = lane >> 4, l16 = lane & 15;
    const int wm = wave >> 1, wn = wave & 1;
    const int mode = blockIdx.z;
    const unsigned short* xh = (const unsigned short*)(wsb + BY_XH);
    const unsigned short* ph = (const unsigned short*)(wsb + BY_PH);
    const unsigned short* wt = (const unsigned short*)(wsb + BY_WT);
    const float scale = 0.04419417382415922f;

    v4f acc[4][4];
#pragma unroll
    for (int i = 0; i < 4; ++i)
#pragma unroll
        for (int j = 0; j < 4; ++j) acc[i][j] = (v4f){0.f, 0.f, 0.f, 0.f};

    if (mode != 2) {
        const int d0 = blockIdx.y * 128 + wm * 64;
        const int s0 = blockIdx.x * 128 + wn * 64;
        const int mat = (mode == 0) ? 0 : (mode == 1) ? 1 : 3;
        const unsigned short* A = wt + (size_t)mat * WT_MAT_HALFS;   // [d][k]
        const unsigned short* B = (mode == 3) ? ph : xh;             // [s][k]

        for (int kk = 0; kk < 16; ++kk) {
            v8s af[4], bf[4];
#pragma unroll
            for (int i = 0; i < 4; ++i) {
                af[i] = *(const v8s*)(A + (size_t)(d0 + i * 16 + l16) * 512 + kk * 32 + quad * 8);
                bf[i] = *(const v8s*)(B + (size_t)(s0 + i * 16 + l16) * 512 + kk * 32 + quad * 8);
            }
#pragma unroll
            for (int i = 0; i < 4; ++i)
#pragma unroll
                for (int j = 0; j < 4; ++j)
                    acc[i][j] = __builtin_amdgcn_mfma_f32_16x16x32_f16(af[i], bf[j], acc[i][j], 0, 0, 0);
        }

#pragma unroll
        for (int i = 0; i < 4; ++i) {
            int db = d0 + i * 16 + quad * 4;
            int h = db >> 6, dl = db & 63;
            float4 b4 = (mode == 3) ? make_float4(0.f, 0.f, 0.f, 0.f)
                        : (mode == 0) ? *(const float4*)(bq + db)
                                      : *(const float4*)(bk + db);
#pragma unroll
            for (int j = 0; j < 4; ++j) {
                int s = s0 + j * 16 + l16;
                int bb = s >> 11, srow = s & 2047;
                size_t o = ((size_t)(bb * NH + h) * S_LEN + srow) * DHD + dl;
                if (mode == 0) {
                    float4 u4 = *(const float4*)(uvec + db);
                    float4 v4 = *(const float4*)(vvec + db);
                    unsigned short* qu = (unsigned short*)(wsb + BY_QU);
                    unsigned short* qv = (unsigned short*)(wsb + BY_QV);
                    ushort4 pu, pv;
                    pu.x = f2h((acc[i][j][0] + b4.x + u4.x) * scale);
                    pu.y = f2h((acc[i][j][1] + b4.y + u4.y) * scale);
                    pu.z = f2h((acc[i][j][2] + b4.z + u4.z) * scale);
                    pu.w = f2h((acc[i][j][3] + b4.w + u4.w) * scale);
                    pv.x = f2h((acc[i][j][0] + b4.x + v4.x) * scale);
                    pv.y = f2h((acc[i][j][1] + b4.y + v4.y) * scale);
                    pv.z = f2h((acc[i][j][2] + b4.z + v4.z) * scale);
                    pv.w = f2h((acc[i][j][3] + b4.w + v4.w) * scale);
                    *(ushort4*)(qu + o) = pu;
                    *(ushort4*)(qv + o) = pv;
                } else {
                    unsigned short* dst = (unsigned short*)(wsb + (mode == 1 ? BY_K : BY_PB));
                    ushort4 pk;
                    pk.x = f2h(acc[i][j][0] + b4.x);
                    pk.y = f2h(acc[i][j][1] + b4.y);
                    pk.z = f2h(acc[i][j][2] + b4.z);
                    pk.w = f2h(acc[i][j][3] + b4.w);
                    *(ushort4*)(dst + o) = pk;
                }
            }
        }
    } else {
        const int s0 = blockIdx.x * 128 + wm * 64;
        const int d0 = blockIdx.y * 128 + wn * 64;
        const unsigned short* A = xh;                                 // [s][k]
        const unsigned short* B = wt + (size_t)2 * WT_MAT_HALFS;      // [d][k]

        for (int kk = 0; kk < 16; ++kk) {
            v8s af[4], bf[4];
#pragma unroll
            for (int i = 0; i < 4; ++i) {
                af[i] = *(const v8s*)(A + (size_t)(s0 + i * 16 + l16) * 512 + kk * 32 + quad * 8);
                bf[i] = *(const v8s*)(B + (size_t)(d0 + i * 16 + l16) * 512 + kk * 32 + quad * 8);
            }
#pragma unroll
            for (int i = 0; i < 4; ++i)
#pragma unroll
                for (int j = 0; j < 4; ++j)
                    acc[i][j] = __builtin_amdgcn_mfma_f32_16x16x32_f16(af[i], bf[j], acc[i][j], 0, 0, 0);
        }

        unsigned short* vt = (unsigned short*)(wsb + BY_VT);
#pragma unroll
        for (int j = 0; j < 4; ++j) {
            int d = d0 + j * 16 + l16;
            int h = d >> 6, dl = d & 63;
            float bval = bvp[d];
#pragma unroll
            for (int i = 0; i < 4; ++i) {
                int sb = s0 + i * 16 + quad * 4;
                int bb = sb >> 11, srow = sb & 2047;
                size_t o = ((size_t)(bb * NH + h) * DHD + dl) * S_LEN + srow;
                ushort4 pk;
                pk.x = f2h(acc[i][j][0] + bval);
                pk.y = f2h(acc[i][j][1] + bval);
                pk.z = f2h(acc[i][j][2] + bval);
                pk.w = f2h(acc[i][j][3] + bval);
                *(ushort4*)(vt + o) = pk;
            }
        }
    }
}

// ---------------------------------------------------------------------------
// Flash attention, Round-17: q-split + K/V LDS staging (r15 single-buffer)
// + FUSED on-the-fly positional GEMM.
// Block = 64 q-rows (4 waves x 16); k-tiles 0..15 (128 k each).
// Per tile: stage(prev issued) -> bar -> QK^T -> G = pb-window x qv (MFMA,
// 12 j-tiles x 4|5 q-tiles, K=64) stored to Gb[80][204] fp16 -> bar ->
// funnel extraction adds P into sacc -> softmax -> PV -> bar -> stage(t+1).
//   branch A (k<=q):  G row ql,   window jb0A = 1984 + k0 - qb
//   branch B (k>=q+2):G row ql+1, window jb0B = max(k0 - qb - 65, 0)
//   k == q+1 -> 0.  Diagonal tile t_mix = qb>>7 runs both windows (2-pass).
// QU/QV prescaled at producer -> no scale mul here.
// LDS: K 16KB + V 16KB + G 31.9KB = 63.9KB -> 2 blocks/CU.
// ---------------------------------------------------------------------------
__global__ __launch_bounds__(256, 2)
void attn_fused(const unsigned short* __restrict__ qu,
                const unsigned short* __restrict__ kdat,
                const unsigned short* __restrict__ vtg,
                const unsigned short* __restrict__ qvg,
                const unsigned short* __restrict__ pbg,
                unsigned short* __restrict__ ctx)
{
    __shared__ __align__(16) unsigned short Kbuf[8192];     // 16 KB
    __shared__ __align__(16) unsigned short Vbuf[8192];     // 16 KB
    __shared__ __align__(16) unsigned short Gb[80 * GJP];   // 31.9 KB

    const int t = threadIdx.x;
    const int wave = t >> 6, lane = t & 63;
    const int quad = lane >> 4, l16 = lane & 15;
    const int g = blockIdx.x >> 5, qt = blockIdx.x & 31;
    const int qb = qt * 64;
    const int q0w = qb + wave * 16;
    const int ql = wave * 16 + l16;          // q-local in [0,64)
    const int q = qb + ql;
    const int t_mix = qb >> 7;               // diagonal k-tile index
    const int dq = 63 - ql;
    const int pA = dq & 3;
    const int ca_add = (dq - pA) + 4;        // A-read aligned col bias

    const unsigned short* QU = qu   + (size_t)g * HEAD_ELEMS;
    const unsigned short* Kg = kdat + (size_t)g * HEAD_ELEMS;
    const unsigned short* Vg = vtg  + (size_t)g * HEAD_ELEMS;
    const unsigned short* QV = qvg  + (size_t)g * HEAD_ELEMS;
    const unsigned short* Pb = pbg  + (size_t)g * HEAD_ELEMS;

    // staging lane roles (constant per thread)
    const int krow_l = lane >> 3, kch_l = lane & 7;    // within 8-row K group
    const int vrow_l = lane >> 4, vch_l = lane & 15;   // within 4-row V group

#define STAGE_KV(TT)                                                          \
    {                                                                         \
        const int k0s = (TT) * 128;                                           \
        _Pragma("unroll")                                                     \
        for (int jj = 0; jj < 4; ++jj) {                                      \
            const int j = wave * 4 + jj;                                      \
            {                                                                 \
                int kr = j * 8 + krow_l;                                      \
                int kc = kch_l ^ (kr & 7);                                    \
                __builtin_amdgcn_global_load_lds(                             \
                    (const __attribute__((address_space(1))) unsigned int*)   \
                        (Kg + (size_t)(k0s + kr) * DHD + kc * 8),             \
                    (__attribute__((address_space(3))) unsigned int*)         \
                        (Kbuf + j * 512), 16, 0, 0);                          \
            }                                                                 \
            {                                                                 \
                int vr = j * 4 + vrow_l;                                      \
                int vc = vch_l ^ (vr & 15);                                   \
                __builtin_amdgcn_global_load_lds(                             \
                    (const __attribute__((address_space(1))) unsigned int*)   \
                        (Vg + (size_t)vr * S_LEN + k0s + vc * 8),             \
                    (__attribute__((address_space(3))) unsigned int*)         \
                        (Vbuf + j * 512), 16, 0, 0);                          \
            }                                                                 \
        }                                                                     \
    }

#define G_LOAD_AF(JB0)                                                        \
    {                                                                         \
        _Pragma("unroll")                                                     \
        for (int jt2 = 0; jt2 < 3; ++jt2) {                                   \
            int j = (JB0) + (wave * 3 + jt2) * 16 + l16;                      \
            j = j < 0 ? 0 : (j > 2047 ? 2047 : j);                            \
            af0[jt2] = *(const v8s*)(Pb + (size_t)j * DHD + quad * 8);        \
            af1[jt2] = *(const v8s*)(Pb + (size_t)j * DHD + 32 + quad * 8);   \
        }                                                                     \
    }

#define G_MFMA_STORE(NQT)                                                     \
    {                                                                         \
        _Pragma("unroll")                                                     \
        for (int jt2 = 0; jt2 < 3; ++jt2) {                                   \
            const int colb = 4 + (wave * 3 + jt2) * 16 + quad * 4;            \
            _Pragma("unroll")                                                 \
            for (int qt2 = 0; qt2 < (NQT); ++qt2) {                           \
                v4f c = (v4f){0.f, 0.f, 0.f, 0.f};                            \
                c = __builtin_amdgcn_mfma_f32_16x16x32_f16(af0[jt2], qvf0[qt2], c, 0, 0, 0); \
                c = __builtin_amdgcn_mfma_f32_16x16x32_f16(af1[jt2], qvf1[qt2], c, 0, 0, 0); \
                unsigned short* gr = Gb + (qt2 * 16 + l16) * GJP + colb;      \
                *(unsigned*)gr       = pkh(c[0], c[1]);                       \
                *(unsigned*)(gr + 2) = pkh(c[2], c[3]);                       \
            }                                                                 \
        }                                                                     \
    }

// MODE: 0 = unconditional, 1 = only k<=q (diagonal pass A)
#define EXTRACT_A(MODE)                                                       \
    {                                                                         \
        const unsigned short* grA = Gb + ql * GJP;                            \
        _Pragma("unroll")                                                     \
        for (int nt = 0; nt < 8; ++nt) {                                      \
            unsigned short hA[4];                                             \
            g_read4(grA, nt * 16 + quad * 4 + ca_add, pA, hA);                \
            _Pragma("unroll")                                                 \
            for (int reg = 0; reg < 4; ++reg) {                               \
                float pv = h2f(hA[reg]);                                      \
                if (MODE) {                                                   \
                    int k = k0 + nt * 16 + quad * 4 + reg;                    \
                    pv = (k <= q) ? pv : 0.f;                                 \
                }                                                             \
                sacc[nt][reg] += pv;                                          \
            }                                                                 \
        }                                                                     \
    }

// MODE: 0 = unconditional, 1 = zero at k==q+1, 2 = only k>=q+2 (diag pass B)
#define EXTRACT_B(MODE)                                                       \
    {                                                                         \
        const unsigned short* grB = Gb + (ql + 1) * GJP;                      \
        const int Ec = k0 - qb - ql - 2 - jb0B + 4;                           \
        const int pB = Ec & 3;                                                \
        _Pragma("unroll")                                                     \
        for (int nt = 0; nt < 8; ++nt) {                                      \
            int eB = nt * 16 + quad * 4 + Ec;                                 \
            int cB0 = eB - pB; if (cB0 < 0) cB0 = 0;                          \
            unsigned short hB[4];                                             \
            g_read4(grB, cB0, pB, hB);                                        \
            _Pragma("unroll")                                                 \
            for (int reg = 0; reg < 4; ++reg) {                               \
                float pv = h2f(hB[reg]);                                      \
                int k = k0 + nt * 16 + quad * 4 + reg;                        \
                if ((MODE) == 1) pv = (k == q + 1) ? 0.f : pv;                \
                if ((MODE) == 2) pv = (k >= q + 2) ? pv : 0.f;                \
                sacc[nt][reg] += pv;                                          \
            }                                                                 \
        }                                                                     \
    }

    // prologue: stage tile 0; load resident fragments
    STAGE_KV(0)

    // qv fragments (G B-operand): 5 q-tiles (rows qb..qb+79, clamped)
    v8s qvf0[5], qvf1[5];
#pragma unroll
    for (int qt2 = 0; qt2 < 5; ++qt2) {
        int r = qb + qt2 * 16 + l16;
        if (r > 2047) r = 2047;
        qvf0[qt2] = *(const v8s*)(QV + (size_t)r * DHD + quad * 8);
        qvf1[qt2] = *(const v8s*)(QV + (size_t)r * DHD + 32 + quad * 8);
    }
    const v8s bq0 = *(const v8s*)(QU + (size_t)q * DHD + quad * 8);
    const v8s bq1 = *(const v8s*)(QU + (size_t)q * DHD + 32 + quad * 8);

    float m_run = -1e30f, l_run = 0.f;
    v4f accv[4];
#pragma unroll
    for (int r = 0; r < 4; ++r) accv[r] = (v4f){0.f, 0.f, 0.f, 0.f};

    for (int tt = 0; tt < 16; ++tt) {
        const int k0 = tt * 128;
        int jb0B = k0 - qb - 65; if (jb0B < 0) jb0B = 0;
        const int jb0_1 = (tt <= t_mix) ? (1984 + k0 - qb) : jb0B;

        // issue pb-window loads early (fly under QK)
        v8s af0[3], af1[3];
        G_LOAD_AF(jb0_1)

        __syncthreads();   // stage(tt) complete & visible

        // QK^T from Kbuf (swizzled ds_read_b128); QU prescaled
        v4f sacc[8];
#pragma unroll
        for (int nt = 0; nt < 8; ++nt) {
            int r = nt * 16 + l16;
            const unsigned short* kl = Kbuf + r * 64;
            v8s a0 = *(const v8s*)(kl + ((quad ^ (r & 7)) * 8));
            v8s a1 = *(const v8s*)(kl + (((4 + quad) ^ (r & 7)) * 8));
            v4f c = (v4f){0.f, 0.f, 0.f, 0.f};
            c = __builtin_amdgcn_mfma_f32_16x16x32_f16(a0, bq0, c, 0, 0, 0);
            c = __builtin_amdgcn_mfma_f32_16x16x32_f16(a1, bq1, c, 0, 0, 0);
            sacc[nt] = c;
        }

        // G window 1 build + extraction (per tile class; block-uniform)
        if (tt < t_mix) {
            G_MFMA_STORE(4)
            __syncthreads();
            EXTRACT_A(0)
        } else if (tt == t_mix) {
            G_MFMA_STORE(4)
            __syncthreads();
            EXTRACT_A(1)
            __syncthreads();          // A reads done before B overwrites G
            G_LOAD_AF(jb0B)
            G_MFMA_STORE(5)
            __syncthreads();
            EXTRACT_B(2)
        } else {
            G_MFMA_STORE(5)
            __syncthreads();
            if (tt == t_mix + 1) {
                EXTRACT_B(1)
            } else {
                EXTRACT_B(0)
            }
        }

        // online softmax (inputs already scaled)
        float tm = -1e30f;
#pragma unroll
        for (int nt = 0; nt < 8; ++nt)
#pragma unroll
            for (int reg = 0; reg < 4; ++reg) tm = fmaxf(tm, sacc[nt][reg]);
        tm = fmaxf(tm, __shfl_xor(tm, 16));
        tm = fmaxf(tm, __shfl_xor(tm, 32));
        float mn = fmaxf(m_run, tm);
        float al = __expf(m_run - mn);
        float rs = 0.f;
#pragma unroll
        for (int nt = 0; nt < 8; ++nt)
#pragma unroll
            for (int reg = 0; reg < 4; ++reg) {
                sacc[nt][reg] = __expf(sacc[nt][reg] - mn);
                rs += sacc[nt][reg];
            }
        rs += __shfl_xor(rs, 16);
        rs += __shfl_xor(rs, 32);
        l_run = l_run * al + rs;
        m_run = mn;

        float alr[4];
#pragma unroll
        for (int reg = 0; reg < 4; ++reg) alr[reg] = __shfl(al, quad * 4 + reg);
#pragma unroll
        for (int ntd = 0; ntd < 4; ++ntd)
#pragma unroll
            for (int reg = 0; reg < 4; ++reg) accv[ntd][reg] *= alr[reg];

        // pack P to fp16 word-pairs
        unsigned pk[8][2];
#pragma unroll
        for (int nt = 0; nt < 8; ++nt) {
            pk[nt][0] = pkh(sacc[nt][0], sacc[nt][1]);
            pk[nt][1] = pkh(sacc[nt][2], sacc[nt][3]);
        }

        // PV: A-fragment via shfl transpose, B from Vbuf (swizzled)
        const int sA = l16 + ((quad & 1) * 32);
        const bool hi = (quad >= 2);
#pragma unroll
        for (int c4 = 0; c4 < 4; ++c4) {
            unsigned a0A = __shfl((int)pk[c4 * 2][0], sA);
            unsigned a1A = __shfl((int)pk[c4 * 2][1], sA);
            unsigned a0B = __shfl((int)pk[c4 * 2][0], sA + 16);
            unsigned a1B = __shfl((int)pk[c4 * 2][1], sA + 16);
            unsigned b0A = __shfl((int)pk[c4 * 2 + 1][0], sA);
            unsigned b1A = __shfl((int)pk[c4 * 2 + 1][1], sA);
            unsigned b0B = __shfl((int)pk[c4 * 2 + 1][0], sA + 16);
            unsigned b1B = __shfl((int)pk[c4 * 2 + 1][1], sA + 16);
            union { unsigned u[4]; v8s v; } apu;
            apu.u[0] = hi ? b0A : a0A;
            apu.u[1] = hi ? b1A : a1A;
            apu.u[2] = hi ? b0B : a0B;
            apu.u[3] = hi ? b1B : a1B;
#pragma unroll
            for (int ntd = 0; ntd < 4; ++ntd) {
                int d = ntd * 16 + l16;
                v8s bv8 = *(const v8s*)(Vbuf + d * 128 +
                                        (((c4 * 4 + quad) ^ (d & 15)) * 8));
                accv[ntd] = __builtin_amdgcn_mfma_f32_16x16x32_f16(apu.v, bv8, accv[ntd], 0, 0, 0);
            }
        }

        __syncthreads();   // all waves done with Kbuf/Vbuf/Gb
        if (tt < 15) STAGE_KV(tt + 1)
    }
#undef STAGE_KV
#undef G_LOAD_AF
#undef G_MFMA_STORE
#undef EXTRACT_A
#undef EXTRACT_B

    // epilogue: each wave owns its 16 q-rows completely.
    const int bb = g >> 3, h = g & 7;
    float inv[4];
#pragma unroll
    for (int reg = 0; reg < 4; ++reg)
        inv[reg] = 1.f / __shfl(l_run, quad * 4 + reg);
#pragma unroll
    for (int ntd = 0; ntd < 4; ++ntd)
#pragma unroll
        for (int reg = 0; reg < 4; ++reg) {
            int qq = q0w + quad * 4 + reg;
            ctx[((size_t)(bb * S_LEN + qq)) * DM + h * DHD + ntd * 16 + l16] =
                f2h(accv[ntd][reg] * inv[reg]);
        }
}

// ---------------------------------------------------------------------------
// out_mfma: out(fp32)[s][n] = ctx(fp16) @ Wo + bo.  SWAPPED: C[n][s] ->
// float4 stores.  grid (32, 4): x = s-tile(128), y = n-tile(128).
// ---------------------------------------------------------------------------
__global__ __launch_bounds__(256)
void out_mfma(const float* __restrict__ bo, const char* __restrict__ wsb,
              float* __restrict__ out)
{
    const int t = threadIdx.x;
    const int wave = t >> 6, lane = t & 63;
    const int quad = lane >> 4, l16 = lane & 15;
    const int wm = wave >> 1, wn = wave & 1;
    const int n0 = blockIdx.y * 128 + wm * 64;
    const int s0 = blockIdx.x * 128 + wn * 64;
    const unsigned short* A = (const unsigned short*)(wsb + BY_WT) + (size_t)4 * WT_MAT_HALFS;
    const unsigned short* B = (const unsigned short*)(wsb + BY_CTX);

    v4f acc[4][4];
#pragma unroll
    for (int i = 0; i < 4; ++i)
#pragma unroll
        for (int j = 0; j < 4; ++j) acc[i][j] = (v4f){0.f, 0.f, 0.f, 0.f};

    for (int kk = 0; kk < 16; ++kk) {
        v8s af[4], bf[4];
#pragma unroll
        for (int i = 0; i < 4; ++i) {
            af[i] = *(const v8s*)(A + (size_t)(n0 + i * 16 + l16) * 512 + kk * 32 + quad * 8);
            bf[i] = *(const v8s*)(B + (size_t)(s0 + i * 16 + l16) * 512 + kk * 32 + quad * 8);
        }
#pragma unroll
        for (int i = 0; i < 4; ++i)
#pragma unroll
            for (int j = 0; j < 4; ++j)
                acc[i][j] = __builtin_amdgcn_mfma_f32_16x16x32_f16(af[i], bf[j], acc[i][j], 0, 0, 0);
    }

#pragma unroll
    for (int i = 0; i < 4; ++i) {
        int nb = n0 + i * 16 + quad * 4;
        float4 b4 = *(const float4*)(bo + nb);
#pragma unroll
        for (int j = 0; j < 4; ++j) {
            int s = s0 + j * 16 + l16;
            *(float4*)(out + (size_t)s * DM + nb) =
                make_float4(acc[i][j][0] + b4.x, acc[i][j][1] + b4.y,
                            acc[i][j][2] + b4.z, acc[i][j][3] + b4.w);
        }
    }
}

// Fallback when ws_size is insufficient: clean mismatch instead of OOB writes.
__global__ void zero_fill(float* __restrict__ p, int n)
{
    int i = blockIdx.x * 256 + threadIdx.x;
    if (i < n) p[i] = 0.f;
}

// ---------------------------------------------------------------------------
extern "C" void kernel_launch(void* const* d_in, const int* in_sizes, int n_in,
                              void* d_out, int out_size, void* d_ws, size_t ws_size,
                              hipStream_t stream)
{
    const float* x   = (const float*)d_in[0];
    const float* pos = (const float*)d_in[1];
    const float* Wq  = (const float*)d_in[2];
    const float* bq  = (const float*)d_in[3];
    const float* Wk  = (const float*)d_in[4];
    const float* bk  = (const float*)d_in[5];
    const float* Wv  = (const float*)d_in[6];
    const float* bv  = (const float*)d_in[7];
    const float* Wp  = (const float*)d_in[8];
    const float* u   = (const float*)d_in[9];
    const float* v   = (const float*)d_in[10];
    const float* Wo  = (const float*)d_in[11];
    const float* bo  = (const float*)d_in[12];
    char* wsb  = (char*)d_ws;
    float* out = (float*)d_out;

    // Workspace guard (no Ppos tensor anymore).
    if (ws_size < (size_t)BY_END + 1024) {
        zero_fill<<<(out_size + 255) / 256, 256, 0, stream>>>(out, out_size);
        return;
    }

    // 1. dtype prep
    conv_inputs<<<dim3(2048, 1, 2), 256, 0, stream>>>(x, pos, wsb);
    conv_wt<<<dim3(8, 8, 5), 256, 0, stream>>>(Wq, Wk, Wv, Wp, Wo, wsb);

    // 2. projections (fp16 MFMA; QU/QV prescaled)
    proj_mfma<<<dim3(32, 4, 4), 256, 0, stream>>>(bq, bk, bv, u, v, wsb);

    // 3. fused attention (single dispatch, all 16 batch-heads)
    attn_fused<<<dim3(NBH * 32), 256, 0, stream>>>(
        (const unsigned short*)(wsb + BY_QU),
        (const unsigned short*)(wsb + BY_K),
        (const unsigned short*)(wsb + BY_VT),
        (const unsigned short*)(wsb + BY_QV),
        (const unsigned short*)(wsb + BY_PB),
        (unsigned short*)(wsb + BY_CTX));

    // 4. output projection (fp16 MFMA, fp32 out)
    out_mfma<<<dim3(32, 4), 256, 0, stream>>>(bo, wsb, out);
}

// Round 6
// 203.507 us; speedup vs baseline: 1.2802x; 1.1295x over previous
//
#include <hip/hip_runtime.h>
#include <hip/hip_fp16.h>
#include <math.h>

// Transformer-XL relative multi-head attention, MI355X. B=2,S=2048,D=512,H=8,dh=64.
// Round-18: (a) T1 XCD swizzle in attn; (b) LDS-staged proj/out GEMMs.
//   r17 post-mortem: fusion won (-27us) but attn FETCH stayed 102MB =
//   8.3x compulsory (12.3MB) -> per-XCD L2 duplication: same-head q-blocks
//   round-robin across 8 XCDs, each L2 refetches K/V/pb.  Fix (a): bijective
//   chunked swizzle vb=(bid&7)*64+(bid>>3): each XCD owns 2 whole heads
//   (1.5MB < 4MB L2).  Non-attn time invariant ~140us across r14-r17;
//   proj_mfma (8.6 GFLOP) + out_mfma (2.2 GFLOP) still use per-lane
//   16-row-divergent global fragment loads (the serialized-latency disease
//   r15 cured in attn).  Fix (b): same staging template as attn Kbuf --
//   stage A/B 128x64 panels per BK=64 via global_load_lds (xor-swizzled
//   source, linear LDS dest), swizzled ds_read_b128 fragments, epilogues
//   unchanged.  LDS 32KB/block.
//  1. conv_inputs : x,pos fp32 -> fp16.   2. conv_wt: 5 weights -> fp16 W^T.
//  3. proj_mfma   : QU(+u)/QV(+v) PRESCALED, K, Pb [s][d]; VT [d][s].
//  4. attn_fused  : single dispatch, fused pos-GEMM, 16 heads x 32 q-blocks.
//  5. out_mfma    : out(fp32) = ctx @ Wo + bo.

#define S_LEN 2048
#define NH 8
#define DHD 64
#define DM 512
#define NBH 16
#define HEAD_ELEMS (S_LEN * DHD)

// workspace byte offsets
#define BY_QU  0u               // fp16 [16][2048][64]  4 MB  (prescaled q+u)
#define BY_QV  4194304u         // fp16 [16][2048][64]  4 MB  (prescaled q+v)
#define BY_K   8388608u         // fp16 [16][2048][64]  4 MB
#define BY_VT  12582912u        // fp16 [16][64][2048]  4 MB
#define BY_PB  16777216u        // fp16 [16][2048][64]  4 MB
#define BY_XH  20971520u        // fp16 [2][2048][512]  4 MB
#define BY_PH  25165824u        // fp16 [2][2048][512]  4 MB
#define BY_WT  29360128u        // fp16 [5][512][512] transposed, 2.62 MB
#define BY_CTX 31981568u        // fp16 [2][2048][512]  4 MB
#define BY_END 36175872u        // end of used workspace
#define WT_MAT_HALFS 262144u

#define GJP 204                 // G row pitch in halfs (408 B)

typedef short v8s __attribute__((ext_vector_type(8)));
typedef float v4f __attribute__((ext_vector_type(4)));

static __device__ __forceinline__ unsigned short f2h(float f) {
    __half h = __float2half(f);
    return *reinterpret_cast<unsigned short*>(&h);
}
static __device__ __forceinline__ float h2f(unsigned short u) {
    __half h = *reinterpret_cast<__half*>(&u);
    return __half2float(h);
}
static __device__ __forceinline__ unsigned pkh(float a, float b) {
    return (unsigned)f2h(a) | ((unsigned)f2h(b) << 16);
}

// read 4 halfs at offset p..p+3 from the 8-half aligned window starting at
// col c0 (c0 % 4 == 0) of LDS row `grow`.  p in 0..3, per-lane constant.
static __device__ __forceinline__ void g_read4(const unsigned short* grow,
                                               int c0, int p,
                                               unsigned short h[4])
{
    uint2 w0 = *(const uint2*)(grow + c0);
    uint2 w1 = *(const uint2*)(grow + c0 + 4);
    unsigned y0 = (p & 2) ? w0.y : w0.x;
    unsigned y1 = (p & 2) ? w1.x : w0.y;
    unsigned y2 = (p & 2) ? w1.y : w1.x;
    unsigned s = (unsigned)(p & 1) * 16u;
    unsigned v01 = __builtin_amdgcn_alignbit(y1, y0, s);
    unsigned v23 = __builtin_amdgcn_alignbit(y2, y1, s);
    h[0] = (unsigned short)(v01 & 0xffff);
    h[1] = (unsigned short)(v01 >> 16);
    h[2] = (unsigned short)(v23 & 0xffff);
    h[3] = (unsigned short)(v23 >> 16);
}

// ---------------------------------------------------------------------------
// conv_inputs: fp32 -> fp16, 4 els/thread. z: 0 = x, 1 = pos.
// ---------------------------------------------------------------------------
__global__ __launch_bounds__(256)
void conv_inputs(const float* __restrict__ x, const float* __restrict__ pos,
                 char* __restrict__ wsb)
{
    const float* src = blockIdx.z ? pos : x;
    unsigned short* dst = (unsigned short*)(wsb + (blockIdx.z ? BY_PH : BY_XH));
    int i = (blockIdx.x * 256 + threadIdx.x) * 4;
    float4 a = *(const float4*)(src + i);
    ushort4 p;
    p.x = f2h(a.x); p.y = f2h(a.y); p.z = f2h(a.z); p.w = f2h(a.w);
    *(ushort4*)(dst + i) = p;
}

// ---------------------------------------------------------------------------
// conv_wt: WT[m][n][k] = W_m[k][n] fp16. 64x64 LDS tile transpose.
// ---------------------------------------------------------------------------
__global__ __launch_bounds__(256)
void conv_wt(const float* __restrict__ Wq, const float* __restrict__ Wk,
             const float* __restrict__ Wv, const float* __restrict__ Wp,
             const float* __restrict__ Wo, char* __restrict__ wsb)
{
    __shared__ float T[64][65];
    const float* W = (blockIdx.z == 0) ? Wq : (blockIdx.z == 1) ? Wk :
                     (blockIdx.z == 2) ? Wv : (blockIdx.z == 3) ? Wp : Wo;
    unsigned short* WT = (unsigned short*)(wsb + BY_WT) + blockIdx.z * WT_MAT_HALFS;
    const int n0 = blockIdx.x * 64, k0 = blockIdx.y * 64;
    const int t = threadIdx.x;
#pragma unroll
    for (int i = 0; i < 4; ++i) {
        int f = t + i * 256;
        int row = f >> 4, c4 = f & 15;
        *(float4*)&T[row][c4 * 4] = *(const float4*)(W + (size_t)(k0 + row) * 512 + n0 + c4 * 4);
    }
    __syncthreads();
#pragma unroll
    for (int i = 0; i < 4; ++i) {
        int f = t + i * 256;
        int n = f >> 4, k4 = f & 15;
        ushort4 p;
        p.x = f2h(T[k4 * 4 + 0][n]); p.y = f2h(T[k4 * 4 + 1][n]);
        p.z = f2h(T[k4 * 4 + 2][n]); p.w = f2h(T[k4 * 4 + 3][n]);
        *(ushort4*)(WT + (size_t)(n0 + n) * 512 + k0 + k4 * 4) = p;
    }
}

// ---------------------------------------------------------------------------
// proj_mfma, Round-18: LDS-staged GEMM (attn-Kbuf staging template).
// Block computes a 128x128 output tile over K=512 in 8 BK=64 steps.
// Per step: stage A-panel 128x64 + B-panel 128x64 (16KB each) via
// global_load_lds (src chunk xor-swizzled, LDS linear), barrier, swizzled
// ds_read_b128 fragments, 32 MFMA/wave, barrier, stage next.
// modes 0(Q),1(K),3(P): A = WT[d][k], B = xh/ph[s][k]  (SWAPPED C[d][s])
// mode 2(V):            A = xh[s][k], B = WT_v[d][k]   (C[s][d] -> VT store)
// Epilogues identical to r17 (verified).
// ---------------------------------------------------------------------------
__global__ __launch_bounds__(256)
void proj_mfma(const float* __restrict__ bq, const float* __restrict__ bk,
               const float* __restrict__ bvp,
               const float* __restrict__ uvec, const float* __restrict__ vvec,
               char* __restrict__ wsb)
{
    __shared__ __align__(16) unsigned short Abuf[8192];   // 16 KB: 128 rows x 64
    __shared__ __align__(16) unsigned short Bbuf[8192];   // 16 KB

    const int t = threadIdx.x;
    const int wave = t >> 6, lane = t & 63;
    const int quad = lane >> 4, l16 = lane & 15;
    const int wm = wave >> 1, wn = wave & 1;
    const int mode = blockIdx.z;
    const unsigned short* xh = (const unsigned short*)(wsb + BY_XH);
    const unsigned short* ph = (const unsigned short*)(wsb + BY_PH);
    const unsigned short* wt = (const unsigned short*)(wsb + BY_WT);
    const float scale = 0.04419417382415922f;

    const unsigned short* matA;
    const unsigned short* matB;
    if (mode != 2) {
        const int mat = (mode == 0) ? 0 : (mode == 1) ? 1 : 3;
        matA = wt + (size_t)mat * WT_MAT_HALFS + (size_t)(blockIdx.y * 128) * 512;
        matB = ((mode == 3) ? ph : xh) + (size_t)(blockIdx.x * 128) * 512;
    } else {
        matA = xh + (size_t)(blockIdx.x * 128) * 512;
        matB = wt + (size_t)2 * WT_MAT_HALFS + (size_t)(blockIdx.y * 128) * 512;
    }

    const int rowl = lane >> 3, chl = lane & 7;   // 8 rows / 8 chunks per inst

#define PSTAGE(KB)                                                            \
    {                                                                         \
        _Pragma("unroll")                                                     \
        for (int jj = 0; jj < 4; ++jj) {                                      \
            const int j = wave * 4 + jj;                                      \
            const int r = j * 8 + rowl;                                       \
            const int c = chl ^ (r & 7);                                      \
            __builtin_amdgcn_global_load_lds(                                 \
                (const __attribute__((address_space(1))) unsigned int*)       \
                    (matA + (size_t)r * 512 + (KB) * 64 + c * 8),             \
                (__attribute__((address_space(3))) unsigned int*)             \
                    (Abuf + j * 512), 16, 0, 0);                              \
            __builtin_amdgcn_global_load_lds(                                 \
                (const __attribute__((address_space(1))) unsigned int*)       \
                    (matB + (size_t)r * 512 + (KB) * 64 + c * 8),             \
                (__attribute__((address_space(3))) unsigned int*)             \
                    (Bbuf + j * 512), 16, 0, 0);                              \
        }                                                                     \
    }

    v4f acc[4][4];
#pragma unroll
    for (int i = 0; i < 4; ++i)
#pragma unroll
        for (int j = 0; j < 4; ++j) acc[i][j] = (v4f){0.f, 0.f, 0.f, 0.f};

    PSTAGE(0)
    for (int kb = 0; kb < 8; ++kb) {
        __syncthreads();
        v8s af0[4], af1[4], bf0[4], bf1[4];
#pragma unroll
        for (int i = 0; i < 4; ++i) {
            int rA = wm * 64 + i * 16 + l16;
            const unsigned short* al = Abuf + rA * 64;
            af0[i] = *(const v8s*)(al + ((quad ^ (rA & 7)) * 8));
            af1[i] = *(const v8s*)(al + (((4 + quad) ^ (rA & 7)) * 8));
            int rB = wn * 64 + i * 16 + l16;
            const unsigned short* bl = Bbuf + rB * 64;
            bf0[i] = *(const v8s*)(bl + ((quad ^ (rB & 7)) * 8));
            bf1[i] = *(const v8s*)(bl + (((4 + quad) ^ (rB & 7)) * 8));
        }
#pragma unroll
        for (int i = 0; i < 4; ++i)
#pragma unroll
            for (int j = 0; j < 4; ++j) {
                acc[i][j] = __builtin_amdgcn_mfma_f32_16x16x32_f16(af0[i], bf0[j], acc[i][j], 0, 0, 0);
                acc[i][j] = __builtin_amdgcn_mfma_f32_16x16x32_f16(af1[i], bf1[j], acc[i][j], 0, 0, 0);
            }
        __syncthreads();
        if (kb < 7) PSTAGE(kb + 1)
    }
#undef PSTAGE

    if (mode != 2) {
        const int d0 = blockIdx.y * 128 + wm * 64;
        const int s0 = blockIdx.x * 128 + wn * 64;
#pragma unroll
        for (int i = 0; i < 4; ++i) {
            int db = d0 + i * 16 + quad * 4;
            int h = db >> 6, dl = db & 63;
            float4 b4 = (mode == 3) ? make_float4(0.f, 0.f, 0.f, 0.f)
                        : (mode == 0) ? *(const float4*)(bq + db)
                                      : *(const float4*)(bk + db);
#pragma unroll
            for (int j = 0; j < 4; ++j) {
                int s = s0 + j * 16 + l16;
                int bb = s >> 11, srow = s & 2047;
                size_t o = ((size_t)(bb * NH + h) * S_LEN + srow) * DHD + dl;
                if (mode == 0) {
                    float4 u4 = *(const float4*)(uvec + db);
                    float4 v4 = *(const float4*)(vvec + db);
                    unsigned short* qu = (unsigned short*)(wsb + BY_QU);
                    unsigned short* qv = (unsigned short*)(wsb + BY_QV);
                    ushort4 pu, pv;
                    pu.x = f2h((acc[i][j][0] + b4.x + u4.x) * scale);
                    pu.y = f2h((acc[i][j][1] + b4.y + u4.y) * scale);
                    pu.z = f2h((acc[i][j][2] + b4.z + u4.z) * scale);
                    pu.w = f2h((acc[i][j][3] + b4.w + u4.w) * scale);
                    pv.x = f2h((acc[i][j][0] + b4.x + v4.x) * scale);
                    pv.y = f2h((acc[i][j][1] + b4.y + v4.y) * scale);
                    pv.z = f2h((acc[i][j][2] + b4.z + v4.z) * scale);
                    pv.w = f2h((acc[i][j][3] + b4.w + v4.w) * scale);
                    *(ushort4*)(qu + o) = pu;
                    *(ushort4*)(qv + o) = pv;
                } else {
                    unsigned short* dst = (unsigned short*)(wsb + (mode == 1 ? BY_K : BY_PB));
                    ushort4 pk;
                    pk.x = f2h(acc[i][j][0] + b4.x);
                    pk.y = f2h(acc[i][j][1] + b4.y);
                    pk.z = f2h(acc[i][j][2] + b4.z);
                    pk.w = f2h(acc[i][j][3] + b4.w);
                    *(ushort4*)(dst + o) = pk;
                }
            }
        }
    } else {
        const int s0 = blockIdx.x * 128 + wm * 64;
        const int d0 = blockIdx.y * 128 + wn * 64;
        unsigned short* vt = (unsigned short*)(wsb + BY_VT);
#pragma unroll
        for (int j = 0; j < 4; ++j) {
            int d = d0 + j * 16 + l16;
            int h = d >> 6, dl = d & 63;
            float bval = bvp[d];
#pragma unroll
            for (int i = 0; i < 4; ++i) {
                int sb = s0 + i * 16 + quad * 4;
                int bb = sb >> 11, srow = sb & 2047;
                size_t o = ((size_t)(bb * NH + h) * DHD + dl) * S_LEN + srow;
                ushort4 pk;
                pk.x = f2h(acc[i][j][0] + bval);
                pk.y = f2h(acc[i][j][1] + bval);
                pk.z = f2h(acc[i][j][2] + bval);
                pk.w = f2h(acc[i][j][3] + bval);
                *(ushort4*)(vt + o) = pk;
            }
        }
    }
}

// ---------------------------------------------------------------------------
// Flash attention, Round-18: r17 core + T1 XCD-chunked block swizzle.
// vb = (bid%8)*64 + bid/8  (bijective, 512 = 8*64): each XCD owns 64
// consecutive virtual blocks = 2 whole heads -> K/V/pb L2-resident per XCD
// (1.5MB < 4MB) instead of 8x duplicated fetch.
// ---------------------------------------------------------------------------
__global__ __launch_bounds__(256, 2)
void attn_fused(const unsigned short* __restrict__ qu,
                const unsigned short* __restrict__ kdat,
                const unsigned short* __restrict__ vtg,
                const unsigned short* __restrict__ qvg,
                const unsigned short* __restrict__ pbg,
                unsigned short* __restrict__ ctx)
{
    __shared__ __align__(16) unsigned short Kbuf[8192];     // 16 KB
    __shared__ __align__(16) unsigned short Vbuf[8192];     // 16 KB
    __shared__ __align__(16) unsigned short Gb[80 * GJP];   // 31.9 KB

    const int t = threadIdx.x;
    const int wave = t >> 6, lane = t & 63;
    const int quad = lane >> 4, l16 = lane & 15;
    const int vb = ((blockIdx.x & 7) << 6) | (blockIdx.x >> 3);   // T1 swizzle
    const int g = vb >> 5, qt = vb & 31;
    const int qb = qt * 64;
    const int q0w = qb + wave * 16;
    const int ql = wave * 16 + l16;          // q-local in [0,64)
    const int q = qb + ql;
    const int t_mix = qb >> 7;               // diagonal k-tile index
    const int dq = 63 - ql;
    const int pA = dq & 3;
    const int ca_add = (dq - pA) + 4;        // A-read aligned col bias

    const unsigned short* QU = qu   + (size_t)g * HEAD_ELEMS;
    const unsigned short* Kg = kdat + (size_t)g * HEAD_ELEMS;
    const unsigned short* Vg = vtg  + (size_t)g * HEAD_ELEMS;
    const unsigned short* QV = qvg  + (size_t)g * HEAD_ELEMS;
    const unsigned short* Pb = pbg  + (size_t)g * HEAD_ELEMS;

    // staging lane roles (constant per thread)
    const int krow_l = lane >> 3, kch_l = lane & 7;    // within 8-row K group
    const int vrow_l = lane >> 4, vch_l = lane & 15;   // within 4-row V group

#define STAGE_KV(TT)                                                          \
    {                                                                         \
        const int k0s = (TT) * 128;                                           \
        _Pragma("unroll")                                                     \
        for (int jj = 0; jj < 4; ++jj) {                                      \
            const int j = wave * 4 + jj;                                      \
            {                                                                 \
                int kr = j * 8 + krow_l;                                      \
                int kc = kch_l ^ (kr & 7);                                    \
                __builtin_amdgcn_global_load_lds(                             \
                    (const __attribute__((address_space(1))) unsigned int*)   \
                        (Kg + (size_t)(k0s + kr) * DHD + kc * 8),             \
                    (__attribute__((address_space(3))) unsigned int*)         \
                        (Kbuf + j * 512), 16, 0, 0);                          \
            }                                                                 \
            {                                                                 \
                int vr = j * 4 + vrow_l;                                      \
                int vc = vch_l ^ (vr & 15);                                   \
                __builtin_amdgcn_global_load_lds(                             \
                    (const __attribute__((address_space(1))) unsigned int*)   \
                        (Vg + (size_t)vr * S_LEN + k0s + vc * 8),             \
                    (__attribute__((address_space(3))) unsigned int*)         \
                        (Vbuf + j * 512), 16, 0, 0);                          \
            }                                                                 \
        }                                                                     \
    }

#define G_LOAD_AF(JB0)                                                        \
    {                                                                         \
        _Pragma("unroll")                                                     \
        for (int jt2 = 0; jt2 < 3; ++jt2) {                                   \
            int j = (JB0) + (wave * 3 + jt2) * 16 + l16;                      \
            j = j < 0 ? 0 : (j > 2047 ? 2047 : j);                            \
            af0[jt2] = *(const v8s*)(Pb + (size_t)j * DHD + quad * 8);        \
            af1[jt2] = *(const v8s*)(Pb + (size_t)j * DHD + 32 + quad * 8);   \
        }                                                                     \
    }

#define G_MFMA_STORE(NQT)                                                     \
    {                                                                         \
        _Pragma("unroll")                                                     \
        for (int jt2 = 0; jt2 < 3; ++jt2) {                                   \
            const int colb = 4 + (wave * 3 + jt2) * 16 + quad * 4;            \
            _Pragma("unroll")                                                 \
            for (int qt2 = 0; qt2 < (NQT); ++qt2) {                           \
                v4f c = (v4f){0.f, 0.f, 0.f, 0.f};                            \
                c = __builtin_amdgcn_mfma_f32_16x16x32_f16(af0[jt2], qvf0[qt2], c, 0, 0, 0); \
                c = __builtin_amdgcn_mfma_f32_16x16x32_f16(af1[jt2], qvf1[qt2], c, 0, 0, 0); \
                unsigned short* gr = Gb + (qt2 * 16 + l16) * GJP + colb;      \
                *(unsigned*)gr       = pkh(c[0], c[1]);                       \
                *(unsigned*)(gr + 2) = pkh(c[2], c[3]);                       \
            }                                                                 \
        }                                                                     \
    }

// MODE: 0 = unconditional, 1 = only k<=q (diagonal pass A)
#define EXTRACT_A(MODE)                                                       \
    {                                                                         \
        const unsigned short* grA = Gb + ql * GJP;                            \
        _Pragma("unroll")                                                     \
        for (int nt = 0; nt < 8; ++nt) {                                      \
            unsigned short hA[4];                                             \
            g_read4(grA, nt * 16 + quad * 4 + ca_add, pA, hA);                \
            _Pragma("unroll")                                                 \
            for (int reg = 0; reg < 4; ++reg) {                               \
                float pv = h2f(hA[reg]);                                      \
                if (MODE) {                                                   \
                    int k = k0 + nt * 16 + quad * 4 + reg;                    \
                    pv = (k <= q) ? pv : 0.f;                                 \
                }                                                             \
                sacc[nt][reg] += pv;                                          \
            }                                                                 \
        }                                                                     \
    }

// MODE: 0 = unconditional, 1 = zero at k==q+1, 2 = only k>=q+2 (diag pass B)
#define EXTRACT_B(MODE)                                                       \
    {                                                                         \
        const unsigned short* grB = Gb + (ql + 1) * GJP;                      \
        const int Ec = k0 - qb - ql - 2 - jb0B + 4;                           \
        const int pB = Ec & 3;                                                \
        _Pragma("unroll")                                                     \
        for (int nt = 0; nt < 8; ++nt) {                                      \
            int eB = nt * 16 + quad * 4 + Ec;                                 \
            int cB0 = eB - pB; if (cB0 < 0) cB0 = 0;                          \
            unsigned short hB[4];                                             \
            g_read4(grB, cB0, pB, hB);                                        \
            _Pragma("unroll")                                                 \
            for (int reg = 0; reg < 4; ++reg) {                               \
                float pv = h2f(hB[reg]);                                      \
                int k = k0 + nt * 16 + quad * 4 + reg;                        \
                if ((MODE) == 1) pv = (k == q + 1) ? 0.f : pv;                \
                if ((MODE) == 2) pv = (k >= q + 2) ? pv : 0.f;                \
                sacc[nt][reg] += pv;                                          \
            }                                                                 \
        }                                                                     \
    }

    // prologue: stage tile 0; load resident fragments
    STAGE_KV(0)

    // qv fragments (G B-operand): 5 q-tiles (rows qb..qb+79, clamped)
    v8s qvf0[5], qvf1[5];
#pragma unroll
    for (int qt2 = 0; qt2 < 5; ++qt2) {
        int r = qb + qt2 * 16 + l16;
        if (r > 2047) r = 2047;
        qvf0[qt2] = *(const v8s*)(QV + (size_t)r * DHD + quad * 8);
        qvf1[qt2] = *(const v8s*)(QV + (size_t)r * DHD + 32 + quad * 8);
    }
    const v8s bq0 = *(const v8s*)(QU + (size_t)q * DHD + quad * 8);
    const v8s bq1 = *(const v8s*)(QU + (size_t)q * DHD + 32 + quad * 8);

    float m_run = -1e30f, l_run = 0.f;
    v4f accv[4];
#pragma unroll
    for (int r = 0; r < 4; ++r) accv[r] = (v4f){0.f, 0.f, 0.f, 0.f};

    for (int tt = 0; tt < 16; ++tt) {
        const int k0 = tt * 128;
        int jb0B = k0 - qb - 65; if (jb0B < 0) jb0B = 0;
        const int jb0_1 = (tt <= t_mix) ? (1984 + k0 - qb) : jb0B;

        // issue pb-window loads early (fly under QK)
        v8s af0[3], af1[3];
        G_LOAD_AF(jb0_1)

        __syncthreads();   // stage(tt) complete & visible

        // QK^T from Kbuf (swizzled ds_read_b128); QU prescaled
        v4f sacc[8];
#pragma unroll
        for (int nt = 0; nt < 8; ++nt) {
            int r = nt * 16 + l16;
            const unsigned short* kl = Kbuf + r * 64;
            v8s a0 = *(const v8s*)(kl + ((quad ^ (r & 7)) * 8));
            v8s a1 = *(const v8s*)(kl + (((4 + quad) ^ (r & 7)) * 8));
            v4f c = (v4f){0.f, 0.f, 0.f, 0.f};
            c = __builtin_amdgcn_mfma_f32_16x16x32_f16(a0, bq0, c, 0, 0, 0);
            c = __builtin_amdgcn_mfma_f32_16x16x32_f16(a1, bq1, c, 0, 0, 0);
            sacc[nt] = c;
        }

        // G window 1 build + extraction (per tile class; block-uniform)
        if (tt < t_mix) {
            G_MFMA_STORE(4)
            __syncthreads();
            EXTRACT_A(0)
        } else if (tt == t_mix) {
            G_MFMA_STORE(4)
            __syncthreads();
            EXTRACT_A(1)
            __syncthreads();          // A reads done before B overwrites G
            G_LOAD_AF(jb0B)
            G_MFMA_STORE(5)
            __syncthreads();
            EXTRACT_B(2)
        } else {
            G_MFMA_STORE(5)
            __syncthreads();
            if (tt == t_mix + 1) {
                EXTRACT_B(1)
            } else {
                EXTRACT_B(0)
            }
        }

        // online softmax (inputs already scaled)
        float tm = -1e30f;
#pragma unroll
        for (int nt = 0; nt < 8; ++nt)
#pragma unroll
            for (int reg = 0; reg < 4; ++reg) tm = fmaxf(tm, sacc[nt][reg]);
        tm = fmaxf(tm, __shfl_xor(tm, 16));
        tm = fmaxf(tm, __shfl_xor(tm, 32));
        float mn = fmaxf(m_run, tm);
        float al = __expf(m_run - mn);
        float rs = 0.f;
#pragma unroll
        for (int nt = 0; nt < 8; ++nt)
#pragma unroll
            for (int reg = 0; reg < 4; ++reg) {
                sacc[nt][reg] = __expf(sacc[nt][reg] - mn);
                rs += sacc[nt][reg];
            }
        rs += __shfl_xor(rs, 16);
        rs += __shfl_xor(rs, 32);
        l_run = l_run * al + rs;
        m_run = mn;

        float alr[4];
#pragma unroll
        for (int reg = 0; reg < 4; ++reg) alr[reg] = __shfl(al, quad * 4 + reg);
#pragma unroll
        for (int ntd = 0; ntd < 4; ++ntd)
#pragma unroll
            for (int reg = 0; reg < 4; ++reg) accv[ntd][reg] *= alr[reg];

        // pack P to fp16 word-pairs
        unsigned pk[8][2];
#pragma unroll
        for (int nt = 0; nt < 8; ++nt) {
            pk[nt][0] = pkh(sacc[nt][0], sacc[nt][1]);
            pk[nt][1] = pkh(sacc[nt][2], sacc[nt][3]);
        }

        // PV: A-fragment via shfl transpose, B from Vbuf (swizzled)
        const int sA = l16 + ((quad & 1) * 32);
        const bool hi = (quad >= 2);
#pragma unroll
        for (int c4 = 0; c4 < 4; ++c4) {
            unsigned a0A = __shfl((int)pk[c4 * 2][0], sA);
            unsigned a1A = __shfl((int)pk[c4 * 2][1], sA);
            unsigned a0B = __shfl((int)pk[c4 * 2][0], sA + 16);
            unsigned a1B = __shfl((int)pk[c4 * 2][1], sA + 16);
            unsigned b0A = __shfl((int)pk[c4 * 2 + 1][0], sA);
            unsigned b1A = __shfl((int)pk[c4 * 2 + 1][1], sA);
            unsigned b0B = __shfl((int)pk[c4 * 2 + 1][0], sA + 16);
            unsigned b1B = __shfl((int)pk[c4 * 2 + 1][1], sA + 16);
            union { unsigned u[4]; v8s v; } apu;
            apu.u[0] = hi ? b0A : a0A;
            apu.u[1] = hi ? b1A : a1A;
            apu.u[2] = hi ? b0B : a0B;
            apu.u[3] = hi ? b1B : a1B;
#pragma unroll
            for (int ntd = 0; ntd < 4; ++ntd) {
                int d = ntd * 16 + l16;
                v8s bv8 = *(const v8s*)(Vbuf + d * 128 +
                                        (((c4 * 4 + quad) ^ (d & 15)) * 8));
                accv[ntd] = __builtin_amdgcn_mfma_f32_16x16x32_f16(apu.v, bv8, accv[ntd], 0, 0, 0);
            }
        }

        __syncthreads();   // all waves done with Kbuf/Vbuf/Gb
        if (tt < 15) STAGE_KV(tt + 1)
    }
#undef STAGE_KV
#undef G_LOAD_AF
#undef G_MFMA_STORE
#undef EXTRACT_A
#undef EXTRACT_B

    // epilogue: each wave owns its 16 q-rows completely.
    const int bb = g >> 3, h = g & 7;
    float inv[4];
#pragma unroll
    for (int reg = 0; reg < 4; ++reg)
        inv[reg] = 1.f / __shfl(l_run, quad * 4 + reg);
#pragma unroll
    for (int ntd = 0; ntd < 4; ++ntd)
#pragma unroll
        for (int reg = 0; reg < 4; ++reg) {
            int qq = q0w + quad * 4 + reg;
            ctx[((size_t)(bb * S_LEN + qq)) * DM + h * DHD + ntd * 16 + l16] =
                f2h(accv[ntd][reg] * inv[reg]);
        }
}

// ---------------------------------------------------------------------------
// out_mfma, Round-18: LDS-staged (same template as proj).  A = Wo^T[n][k],
// B = ctx[s][k].  SWAPPED C[n][s] -> float4 stores.  grid (32, 4).
// ---------------------------------------------------------------------------
__global__ __launch_bounds__(256)
void out_mfma(const float* __restrict__ bo, const char* __restrict__ wsb,
              float* __restrict__ out)
{
    __shared__ __align__(16) unsigned short Abuf[8192];   // 16 KB
    __shared__ __align__(16) unsigned short Bbuf[8192];   // 16 KB

    const int t = threadIdx.x;
    const int wave = t >> 6, lane = t & 63;
    const int quad = lane >> 4, l16 = lane & 15;
    const int wm = wave >> 1, wn = wave & 1;
    const unsigned short* matA = (const unsigned short*)(wsb + BY_WT)
                                 + (size_t)4 * WT_MAT_HALFS
                                 + (size_t)(blockIdx.y * 128) * 512;
    const unsigned short* matB = (const unsigned short*)(wsb + BY_CTX)
                                 + (size_t)(blockIdx.x * 128) * 512;

    const int rowl = lane >> 3, chl = lane & 7;

#define OSTAGE(KB)                                                            \
    {                                                                         \
        _Pragma("unroll")                                                     \
        for (int jj = 0; jj < 4; ++jj) {                                      \
            const int j = wave * 4 + jj;                                      \
            const int r = j * 8 + rowl;                                       \
            const int c = chl ^ (r & 7);                                      \
            __builtin_amdgcn_global_load_lds(                                 \
                (const __attribute__((address_space(1))) unsigned int*)       \
                    (matA + (size_t)r * 512 + (KB) * 64 + c * 8),             \
                (__attribute__((address_space(3))) unsigned int*)             \
                    (Abuf + j * 512), 16, 0, 0);                              \
            __builtin_amdgcn_global_load_lds(                                 \
                (const __attribute__((address_space(1))) unsigned int*)       \
                    (matB + (size_t)r * 512 + (KB) * 64 + c * 8),             \
                (__attribute__((address_space(3))) unsigned int*)             \
                    (Bbuf + j * 512), 16, 0, 0);                              \
        }                                                                     \
    }

    v4f acc[4][4];
#pragma unroll
    for (int i = 0; i < 4; ++i)
#pragma unroll
        for (int j = 0; j < 4; ++j) acc[i][j] = (v4f){0.f, 0.f, 0.f, 0.f};

    OSTAGE(0)
    for (int kb = 0; kb < 8; ++kb) {
        __syncthreads();
        v8s af0[4], af1[4], bf0[4], bf1[4];
#pragma unroll
        for (int i = 0; i < 4; ++i) {
            int rA = wm * 64 + i * 16 + l16;
            const unsigned short* al = Abuf + rA * 64;
            af0[i] = *(const v8s*)(al + ((quad ^ (rA & 7)) * 8));
            af1[i] = *(const v8s*)(al + (((4 + quad) ^ (rA & 7)) * 8));
            int rB = wn * 64 + i * 16 + l16;
            const unsigned short* bl = Bbuf + rB * 64;
            bf0[i] = *(const v8s*)(bl + ((quad ^ (rB & 7)) * 8));
            bf1[i] = *(const v8s*)(bl + (((4 + quad) ^ (rB & 7)) * 8));
        }
#pragma unroll
        for (int i = 0; i < 4; ++i)
#pragma unroll
            for (int j = 0; j < 4; ++j) {
                acc[i][j] = __builtin_amdgcn_mfma_f32_16x16x32_f16(af0[i], bf0[j], acc[i][j], 0, 0, 0);
                acc[i][j] = __builtin_amdgcn_mfma_f32_16x16x32_f16(af1[i], bf1[j], acc[i][j], 0, 0, 0);
            }
        __syncthreads();
        if (kb < 7) OSTAGE(kb + 1)
    }
#undef OSTAGE

    const int n0 = blockIdx.y * 128 + wm * 64;
    const int s0 = blockIdx.x * 128 + wn * 64;
#pragma unroll
    for (int i = 0; i < 4; ++i) {
        int nb = n0 + i * 16 + quad * 4;
        float4 b4 = *(const float4*)(bo + nb);
#pragma unroll
        for (int j = 0; j < 4; ++j) {
            int s = s0 + j * 16 + l16;
            *(float4*)(out + (size_t)s * DM + nb) =
                make_float4(acc[i][j][0] + b4.x, acc[i][j][1] + b4.y,
                            acc[i][j][2] + b4.z, acc[i][j][3] + b4.w);
        }
    }
}

// Fallback when ws_size is insufficient: clean mismatch instead of OOB writes.
__global__ void zero_fill(float* __restrict__ p, int n)
{
    int i = blockIdx.x * 256 + threadIdx.x;
    if (i < n) p[i] = 0.f;
}

// ---------------------------------------------------------------------------
extern "C" void kernel_launch(void* const* d_in, const int* in_sizes, int n_in,
                              void* d_out, int out_size, void* d_ws, size_t ws_size,
                              hipStream_t stream)
{
    const float* x   = (const float*)d_in[0];
    const float* pos = (const float*)d_in[1];
    const float* Wq  = (const float*)d_in[2];
    const float* bq  = (const float*)d_in[3];
    const float* Wk  = (const float*)d_in[4];
    const float* bk  = (const float*)d_in[5];
    const float* Wv  = (const float*)d_in[6];
    const float* bv  = (const float*)d_in[7];
    const float* Wp  = (const float*)d_in[8];
    const float* u   = (const float*)d_in[9];
    const float* v   = (const float*)d_in[10];
    const float* Wo  = (const float*)d_in[11];
    const float* bo  = (const float*)d_in[12];
    char* wsb  = (char*)d_ws;
    float* out = (float*)d_out;

    // Workspace guard (no Ppos tensor anymore).
    if (ws_size < (size_t)BY_END + 1024) {
        zero_fill<<<(out_size + 255) / 256, 256, 0, stream>>>(out, out_size);
        return;
    }

    // 1. dtype prep
    conv_inputs<<<dim3(2048, 1, 2), 256, 0, stream>>>(x, pos, wsb);
    conv_wt<<<dim3(8, 8, 5), 256, 0, stream>>>(Wq, Wk, Wv, Wp, Wo, wsb);

    // 2. projections (fp16 MFMA, LDS-staged; QU/QV prescaled)
    proj_mfma<<<dim3(32, 4, 4), 256, 0, stream>>>(bq, bk, bv, u, v, wsb);

    // 3. fused attention (single dispatch, all 16 batch-heads, XCD-swizzled)
    attn_fused<<<dim3(NBH * 32), 256, 0, stream>>>(
        (const unsigned short*)(wsb + BY_QU),
        (const unsigned short*)(wsb + BY_K),
        (const unsigned short*)(wsb + BY_VT),
        (const unsigned short*)(wsb + BY_QV),
        (const unsigned short*)(wsb + BY_PB),
        (unsigned short*)(wsb + BY_CTX));

    // 4. output projection (fp16 MFMA, LDS-staged, fp32 out)
    out_mfma<<<dim3(32, 4), 256, 0, stream>>>(bo, wsb, out);
}

// Round 7
// 193.055 us; speedup vs baseline: 1.3495x; 1.0541x over previous
//
#include <hip/hip_runtime.h>
#include <hip/hip_fp16.h>
#include <math.h>

// Transformer-XL relative multi-head attention, MI355X. B=2,S=2048,D=512,H=8,dh=64.
// Round-19: dense LDS-bounce epilogues for proj/out + T5 setprio in attn.
//   r18 post-mortem: T1 swizzle confirmed exactly (attn FETCH 102->10.4MB,
//   HBM 2%) but attn time unchanged (90us; MfmaUtil 14.6 + VALU 35.7 = 50%
//   busy -> intra-block latency/barrier stall at 2 blocks/CU).  Non-attn is
//   ~113us vs ~45us modeled: the three GEMM epilogues still scatter-store
//   16-row-divergent fragments (proj: ushort4 at 128B/4KB-stride rows = 16
//   lines/inst; out: float4 at 2KB-stride rows) -- the r14 store disease.
//   Fix: repack each 128x128 tile through a 64x132 LDS half-tile (ALIASED
//   onto the dead staging buffers; zero extra LDS) and store dense
//   contiguous runs (2 lines/inst).  Math order unchanged -> bit-identical.
//   attn: setprio(1) around the three MFMA clusters (T5, catalog +4-7%).
//  1. conv_inputs : x,pos fp32 -> fp16.   2. conv_wt: 5 weights -> fp16 W^T.
//  3. proj_mfma   : QU(+u)/QV(+v) PRESCALED, K, Pb [s][d]; VT [d][s].
//  4. attn_fused  : single dispatch, fused pos-GEMM, XCD-swizzled.
//  5. out_mfma    : out(fp32) = ctx @ Wo + bo.

#define S_LEN 2048
#define NH 8
#define DHD 64
#define DM 512
#define NBH 16
#define HEAD_ELEMS (S_LEN * DHD)

// workspace byte offsets
#define BY_QU  0u               // fp16 [16][2048][64]  4 MB  (prescaled q+u)
#define BY_QV  4194304u         // fp16 [16][2048][64]  4 MB  (prescaled q+v)
#define BY_K   8388608u         // fp16 [16][2048][64]  4 MB
#define BY_VT  12582912u        // fp16 [16][64][2048]  4 MB
#define BY_PB  16777216u        // fp16 [16][2048][64]  4 MB
#define BY_XH  20971520u        // fp16 [2][2048][512]  4 MB
#define BY_PH  25165824u        // fp16 [2][2048][512]  4 MB
#define BY_WT  29360128u        // fp16 [5][512][512] transposed, 2.62 MB
#define BY_CTX 31981568u        // fp16 [2][2048][512]  4 MB
#define BY_END 36175872u        // end of used workspace
#define WT_MAT_HALFS 262144u

#define GJP 204                 // G row pitch in halfs (408 B)

typedef short v8s __attribute__((ext_vector_type(8)));
typedef float v4f __attribute__((ext_vector_type(4)));

static __device__ __forceinline__ unsigned short f2h(float f) {
    __half h = __float2half(f);
    return *reinterpret_cast<unsigned short*>(&h);
}
static __device__ __forceinline__ float h2f(unsigned short u) {
    __half h = *reinterpret_cast<__half*>(&u);
    return __half2float(h);
}
static __device__ __forceinline__ unsigned pkh(float a, float b) {
    return (unsigned)f2h(a) | ((unsigned)f2h(b) << 16);
}

// read 4 halfs at offset p..p+3 from the 8-half aligned window starting at
// col c0 (c0 % 4 == 0) of LDS row `grow`.  p in 0..3, per-lane constant.
static __device__ __forceinline__ void g_read4(const unsigned short* grow,
                                               int c0, int p,
                                               unsigned short h[4])
{
    uint2 w0 = *(const uint2*)(grow + c0);
    uint2 w1 = *(const uint2*)(grow + c0 + 4);
    unsigned y0 = (p & 2) ? w0.y : w0.x;
    unsigned y1 = (p & 2) ? w1.x : w0.y;
    unsigned y2 = (p & 2) ? w1.y : w1.x;
    unsigned s = (unsigned)(p & 1) * 16u;
    unsigned v01 = __builtin_amdgcn_alignbit(y1, y0, s);
    unsigned v23 = __builtin_amdgcn_alignbit(y2, y1, s);
    h[0] = (unsigned short)(v01 & 0xffff);
    h[1] = (unsigned short)(v01 >> 16);
    h[2] = (unsigned short)(v23 & 0xffff);
    h[3] = (unsigned short)(v23 >> 16);
}

// ---------------------------------------------------------------------------
// conv_inputs: fp32 -> fp16, 4 els/thread. z: 0 = x, 1 = pos.
// ---------------------------------------------------------------------------
__global__ __launch_bounds__(256)
void conv_inputs(const float* __restrict__ x, const float* __restrict__ pos,
                 char* __restrict__ wsb)
{
    const float* src = blockIdx.z ? pos : x;
    unsigned short* dst = (unsigned short*)(wsb + (blockIdx.z ? BY_PH : BY_XH));
    int i = (blockIdx.x * 256 + threadIdx.x) * 4;
    float4 a = *(const float4*)(src + i);
    ushort4 p;
    p.x = f2h(a.x); p.y = f2h(a.y); p.z = f2h(a.z); p.w = f2h(a.w);
    *(ushort4*)(dst + i) = p;
}

// ---------------------------------------------------------------------------
// conv_wt: WT[m][n][k] = W_m[k][n] fp16. 64x64 LDS tile transpose.
// ---------------------------------------------------------------------------
__global__ __launch_bounds__(256)
void conv_wt(const float* __restrict__ Wq, const float* __restrict__ Wk,
             const float* __restrict__ Wv, const float* __restrict__ Wp,
             const float* __restrict__ Wo, char* __restrict__ wsb)
{
    __shared__ float T[64][65];
    const float* W = (blockIdx.z == 0) ? Wq : (blockIdx.z == 1) ? Wk :
                     (blockIdx.z == 2) ? Wv : (blockIdx.z == 3) ? Wp : Wo;
    unsigned short* WT = (unsigned short*)(wsb + BY_WT) + blockIdx.z * WT_MAT_HALFS;
    const int n0 = blockIdx.x * 64, k0 = blockIdx.y * 64;
    const int t = threadIdx.x;
#pragma unroll
    for (int i = 0; i < 4; ++i) {
        int f = t + i * 256;
        int row = f >> 4, c4 = f & 15;
        *(float4*)&T[row][c4 * 4] = *(const float4*)(W + (size_t)(k0 + row) * 512 + n0 + c4 * 4);
    }
    __syncthreads();
#pragma unroll
    for (int i = 0; i < 4; ++i) {
        int f = t + i * 256;
        int n = f >> 4, k4 = f & 15;
        ushort4 p;
        p.x = f2h(T[k4 * 4 + 0][n]); p.y = f2h(T[k4 * 4 + 1][n]);
        p.z = f2h(T[k4 * 4 + 2][n]); p.w = f2h(T[k4 * 4 + 3][n]);
        *(ushort4*)(WT + (size_t)(n0 + n) * 512 + k0 + k4 * 4) = p;
    }
}

// ---------------------------------------------------------------------------
// proj_mfma, Round-19: LDS-staged GEMM + dense LDS-bounce epilogue.
// Staging/MFMA identical to r18.  Epilogue: repack acc through a 64x132
// fp16 LDS half-tile (aliased onto the staging buffers, free after the
// last MFMA barrier) and write dense contiguous runs.
// modes 0(Q),1(K),3(P): tile [d 128][s 128] -> [g][s][dl] rows (128B runs)
// mode 2(V):            tile [s 128][d 128] -> VT [g][dl][s] rows (256B runs)
// ---------------------------------------------------------------------------
__global__ __launch_bounds__(256)
void proj_mfma(const float* __restrict__ bq, const float* __restrict__ bk,
               const float* __restrict__ bvp,
               const float* __restrict__ uvec, const float* __restrict__ vvec,
               char* __restrict__ wsb)
{
    __shared__ __align__(16) unsigned short SRAW[16384];   // 32 KB
    unsigned short* Abuf = SRAW;            // staging A (16 KB)
    unsigned short* Bbuf = SRAW + 8192;     // staging B (16 KB)
    unsigned short* T    = SRAW;            // epilogue repack [64][132] (alias)

    const int t = threadIdx.x;
    const int wave = t >> 6, lane = t & 63;
    const int quad = lane >> 4, l16 = lane & 15;
    const int wm = wave >> 1, wn = wave & 1;
    const int mode = blockIdx.z;
    const unsigned short* xh = (const unsigned short*)(wsb + BY_XH);
    const unsigned short* ph = (const unsigned short*)(wsb + BY_PH);
    const unsigned short* wt = (const unsigned short*)(wsb + BY_WT);

    const unsigned short* matA;
    const unsigned short* matB;
    if (mode != 2) {
        const int mat = (mode == 0) ? 0 : (mode == 1) ? 1 : 3;
        matA = wt + (size_t)mat * WT_MAT_HALFS + (size_t)(blockIdx.y * 128) * 512;
        matB = ((mode == 3) ? ph : xh) + (size_t)(blockIdx.x * 128) * 512;
    } else {
        matA = xh + (size_t)(blockIdx.x * 128) * 512;
        matB = wt + (size_t)2 * WT_MAT_HALFS + (size_t)(blockIdx.y * 128) * 512;
    }

    const int rowl = lane >> 3, chl = lane & 7;   // 8 rows / 8 chunks per inst

#define PSTAGE(KB)                                                            \
    {                                                                         \
        _Pragma("unroll")                                                     \
        for (int jj = 0; jj < 4; ++jj) {                                      \
            const int j = wave * 4 + jj;                                      \
            const int r = j * 8 + rowl;                                       \
            const int c = chl ^ (r & 7);                                      \
            __builtin_amdgcn_global_load_lds(                                 \
                (const __attribute__((address_space(1))) unsigned int*)       \
                    (matA + (size_t)r * 512 + (KB) * 64 + c * 8),             \
                (__attribute__((address_space(3))) unsigned int*)             \
                    (Abuf + j * 512), 16, 0, 0);                              \
            __builtin_amdgcn_global_load_lds(                                 \
                (const __attribute__((address_space(1))) unsigned int*)       \
                    (matB + (size_t)r * 512 + (KB) * 64 + c * 8),             \
                (__attribute__((address_space(3))) unsigned int*)             \
                    (Bbuf + j * 512), 16, 0, 0);                              \
        }                                                                     \
    }

    v4f acc[4][4];
#pragma unroll
    for (int i = 0; i < 4; ++i)
#pragma unroll
        for (int j = 0; j < 4; ++j) acc[i][j] = (v4f){0.f, 0.f, 0.f, 0.f};

    PSTAGE(0)
    for (int kb = 0; kb < 8; ++kb) {
        __syncthreads();
        v8s af0[4], af1[4], bf0[4], bf1[4];
#pragma unroll
        for (int i = 0; i < 4; ++i) {
            int rA = wm * 64 + i * 16 + l16;
            const unsigned short* al = Abuf + rA * 64;
            af0[i] = *(const v8s*)(al + ((quad ^ (rA & 7)) * 8));
            af1[i] = *(const v8s*)(al + (((4 + quad) ^ (rA & 7)) * 8));
            int rB = wn * 64 + i * 16 + l16;
            const unsigned short* bl = Bbuf + rB * 64;
            bf0[i] = *(const v8s*)(bl + ((quad ^ (rB & 7)) * 8));
            bf1[i] = *(const v8s*)(bl + (((4 + quad) ^ (rB & 7)) * 8));
        }
#pragma unroll
        for (int i = 0; i < 4; ++i)
#pragma unroll
            for (int j = 0; j < 4; ++j) {
                acc[i][j] = __builtin_amdgcn_mfma_f32_16x16x32_f16(af0[i], bf0[j], acc[i][j], 0, 0, 0);
                acc[i][j] = __builtin_amdgcn_mfma_f32_16x16x32_f16(af1[i], bf1[j], acc[i][j], 0, 0, 0);
            }
        __syncthreads();
        if (kb < 7) PSTAGE(kb + 1)
    }
#undef PSTAGE
    // NOTE: loop ends with __syncthreads() (kb==7 path) -> staging LDS dead.

    const int d0blk = (mode != 2) ? blockIdx.y * 128 : blockIdx.y * 128;
    const int s0blk = blockIdx.x * 128;

    if (mode != 2) {
        // acc[i][j][reg] = C[d = d0blk + wm*64 + i*16 + quad*4 + reg]
        //                   [s = s0blk + wn*64 + j*16 + l16]
        const int nsel = (mode == 0) ? 2 : 1;
        for (int sel = 0; sel < nsel; ++sel) {
            unsigned short* dstb =
                (mode == 0) ? (unsigned short*)(wsb + (sel ? BY_QV : BY_QU))
                            : (unsigned short*)(wsb + (mode == 1 ? BY_K : BY_PB));
            for (int hs = 0; hs < 2; ++hs) {
                if (wn == hs) {
#pragma unroll
                    for (int i = 0; i < 4; ++i) {
                        int d_loc = wm * 64 + i * 16 + quad * 4;
                        int db = d0blk + d_loc;
                        float4 addv = make_float4(0.f, 0.f, 0.f, 0.f);
                        float sc = 1.f;
                        if (mode == 0) {
                            float4 b4 = *(const float4*)(bq + db);
                            const float* uv = sel ? vvec : uvec;
                            float4 u4 = *(const float4*)(uv + db);
                            addv = make_float4(b4.x + u4.x, b4.y + u4.y,
                                               b4.z + u4.z, b4.w + u4.w);
                            sc = 0.04419417382415922f;
                        } else if (mode == 1) {
                            addv = *(const float4*)(bk + db);
                        }
#pragma unroll
                        for (int j = 0; j < 4; ++j) {
                            int s_loc = j * 16 + l16;
                            ushort4 pk;
                            pk.x = f2h((acc[i][j][0] + addv.x) * sc);
                            pk.y = f2h((acc[i][j][1] + addv.y) * sc);
                            pk.z = f2h((acc[i][j][2] + addv.z) * sc);
                            pk.w = f2h((acc[i][j][3] + addv.w) * sc);
                            *(ushort4*)&T[s_loc * 132 + d_loc] = pk;
                        }
                    }
                }
                __syncthreads();
                {
                    const int col4 = t & 31, rowb = t >> 5;
#pragma unroll
                    for (int ii = 0; ii < 8; ++ii) {
                        int row = rowb + ii * 8;
                        int s = s0blk + hs * 64 + row;
                        int bb = s >> 11, srow = s & 2047;
                        int d = d0blk + col4 * 4;
                        int h = d >> 6, dl = d & 63;
                        *(ushort4*)(dstb + ((size_t)(bb * NH + h) * S_LEN + srow) * DHD + dl) =
                            *(const ushort4*)&T[row * 132 + col4 * 4];
                    }
                }
                __syncthreads();
            }
        }
    } else {
        // acc[i][j][reg] = V[s = s0blk + wm*64 + i*16 + quad*4 + reg]
        //                   [d = d0blk + wn*64 + j*16 + l16]
        unsigned short* vt = (unsigned short*)(wsb + BY_VT);
        for (int hs = 0; hs < 2; ++hs) {
            if (wn == hs) {
#pragma unroll
                for (int j = 0; j < 4; ++j) {
                    int d_loc = j * 16 + l16;
                    int d = d0blk + hs * 64 + d_loc;
                    float bval = bvp[d];
#pragma unroll
                    for (int i = 0; i < 4; ++i) {
                        int s_loc = wm * 64 + i * 16 + quad * 4;
                        ushort4 pk;
                        pk.x = f2h(acc[i][j][0] + bval);
                        pk.y = f2h(acc[i][j][1] + bval);
                        pk.z = f2h(acc[i][j][2] + bval);
                        pk.w = f2h(acc[i][j][3] + bval);
                        *(ushort4*)&T[d_loc * 132 + s_loc] = pk;
                    }
                }
            }
            __syncthreads();
            {
                const int col4 = t & 31, rowb = t >> 5;
#pragma unroll
                for (int ii = 0; ii < 8; ++ii) {
                    int row = rowb + ii * 8;            // d within half
                    int d = d0blk + hs * 64 + row;
                    int h = d >> 6, dl = d & 63;
                    int s = s0blk + col4 * 4;
                    int bb = s >> 11, srow = s & 2047;
                    *(ushort4*)(vt + ((size_t)(bb * NH + h) * DHD + dl) * S_LEN + srow) =
                        *(const ushort4*)&T[row * 132 + col4 * 4];
                }
            }
            __syncthreads();
        }
    }
}

// ---------------------------------------------------------------------------
// Flash attention, Round-19: r18 core (T1 XCD swizzle) + T5 setprio around
// the three MFMA clusters.
// ---------------------------------------------------------------------------
__global__ __launch_bounds__(256, 2)
void attn_fused(const unsigned short* __restrict__ qu,
                const unsigned short* __restrict__ kdat,
                const unsigned short* __restrict__ vtg,
                const unsigned short* __restrict__ qvg,
                const unsigned short* __restrict__ pbg,
                unsigned short* __restrict__ ctx)
{
    __shared__ __align__(16) unsigned short Kbuf[8192];     // 16 KB
    __shared__ __align__(16) unsigned short Vbuf[8192];     // 16 KB
    __shared__ __align__(16) unsigned short Gb[80 * GJP];   // 31.9 KB

    const int t = threadIdx.x;
    const int wave = t >> 6, lane = t & 63;
    const int quad = lane >> 4, l16 = lane & 15;
    const int vb = ((blockIdx.x & 7) << 6) | (blockIdx.x >> 3);   // T1 swizzle
    const int g = vb >> 5, qt = vb & 31;
    const int qb = qt * 64;
    const int q0w = qb + wave * 16;
    const int ql = wave * 16 + l16;          // q-local in [0,64)
    const int q = qb + ql;
    const int t_mix = qb >> 7;               // diagonal k-tile index
    const int dq = 63 - ql;
    const int pA = dq & 3;
    const int ca_add = (dq - pA) + 4;        // A-read aligned col bias

    const unsigned short* QU = qu   + (size_t)g * HEAD_ELEMS;
    const unsigned short* Kg = kdat + (size_t)g * HEAD_ELEMS;
    const unsigned short* Vg = vtg  + (size_t)g * HEAD_ELEMS;
    const unsigned short* QV = qvg  + (size_t)g * HEAD_ELEMS;
    const unsigned short* Pb = pbg  + (size_t)g * HEAD_ELEMS;

    // staging lane roles (constant per thread)
    const int krow_l = lane >> 3, kch_l = lane & 7;    // within 8-row K group
    const int vrow_l = lane >> 4, vch_l = lane & 15;   // within 4-row V group

#define STAGE_KV(TT)                                                          \
    {                                                                         \
        const int k0s = (TT) * 128;                                           \
        _Pragma("unroll")                                                     \
        for (int jj = 0; jj < 4; ++jj) {                                      \
            const int j = wave * 4 + jj;                                      \
            {                                                                 \
                int kr = j * 8 + krow_l;                                      \
                int kc = kch_l ^ (kr & 7);                                    \
                __builtin_amdgcn_global_load_lds(                             \
                    (const __attribute__((address_space(1))) unsigned int*)   \
                        (Kg + (size_t)(k0s + kr) * DHD + kc * 8),             \
                    (__attribute__((address_space(3))) unsigned int*)         \
                        (Kbuf + j * 512), 16, 0, 0);                          \
            }                                                                 \
            {                                                                 \
                int vr = j * 4 + vrow_l;                                      \
                int vc = vch_l ^ (vr & 15);                                   \
                __builtin_amdgcn_global_load_lds(                             \
                    (const __attribute__((address_space(1))) unsigned int*)   \
                        (Vg + (size_t)vr * S_LEN + k0s + vc * 8),             \
                    (__attribute__((address_space(3))) unsigned int*)         \
                        (Vbuf + j * 512), 16, 0, 0);                          \
            }                                                                 \
        }                                                                     \
    }

#define G_LOAD_AF(JB0)                                                        \
    {                                                                         \
        _Pragma("unroll")                                                     \
        for (int jt2 = 0; jt2 < 3; ++jt2) {                                   \
            int j = (JB0) + (wave * 3 + jt2) * 16 + l16;                      \
            j = j < 0 ? 0 : (j > 2047 ? 2047 : j);                            \
            af0[jt2] = *(const v8s*)(Pb + (size_t)j * DHD + quad * 8);        \
            af1[jt2] = *(const v8s*)(Pb + (size_t)j * DHD + 32 + quad * 8);   \
        }                                                                     \
    }

#define G_MFMA_STORE(NQT)                                                     \
    {                                                                         \
        __builtin_amdgcn_s_setprio(1);                                        \
        _Pragma("unroll")                                                     \
        for (int jt2 = 0; jt2 < 3; ++jt2) {                                   \
            const int colb = 4 + (wave * 3 + jt2) * 16 + quad * 4;            \
            _Pragma("unroll")                                                 \
            for (int qt2 = 0; qt2 < (NQT); ++qt2) {                           \
                v4f c = (v4f){0.f, 0.f, 0.f, 0.f};                            \
                c = __builtin_amdgcn_mfma_f32_16x16x32_f16(af0[jt2], qvf0[qt2], c, 0, 0, 0); \
                c = __builtin_amdgcn_mfma_f32_16x16x32_f16(af1[jt2], qvf1[qt2], c, 0, 0, 0); \
                unsigned short* gr = Gb + (qt2 * 16 + l16) * GJP + colb;      \
                *(unsigned*)gr       = pkh(c[0], c[1]);                       \
                *(unsigned*)(gr + 2) = pkh(c[2], c[3]);                       \
            }                                                                 \
        }                                                                     \
        __builtin_amdgcn_s_setprio(0);                                        \
    }

// MODE: 0 = unconditional, 1 = only k<=q (diagonal pass A)
#define EXTRACT_A(MODE)                                                       \
    {                                                                         \
        const unsigned short* grA = Gb + ql * GJP;                            \
        _Pragma("unroll")                                                     \
        for (int nt = 0; nt < 8; ++nt) {                                      \
            unsigned short hA[4];                                             \
            g_read4(grA, nt * 16 + quad * 4 + ca_add, pA, hA);                \
            _Pragma("unroll")                                                 \
            for (int reg = 0; reg < 4; ++reg) {                               \
                float pv = h2f(hA[reg]);                                      \
                if (MODE) {                                                   \
                    int k = k0 + nt * 16 + quad * 4 + reg;                    \
                    pv = (k <= q) ? pv : 0.f;                                 \
                }                                                             \
                sacc[nt][reg] += pv;                                          \
            }                                                                 \
        }                                                                     \
    }

// MODE: 0 = unconditional, 1 = zero at k==q+1, 2 = only k>=q+2 (diag pass B)
#define EXTRACT_B(MODE)                                                       \
    {                                                                         \
        const unsigned short* grB = Gb + (ql + 1) * GJP;                      \
        const int Ec = k0 - qb - ql - 2 - jb0B + 4;                           \
        const int pB = Ec & 3;                                                \
        _Pragma("unroll")                                                     \
        for (int nt = 0; nt < 8; ++nt) {                                      \
            int eB = nt * 16 + quad * 4 + Ec;                                 \
            int cB0 = eB - pB; if (cB0 < 0) cB0 = 0;                          \
            unsigned short hB[4];                                             \
            g_read4(grB, cB0, pB, hB);                                        \
            _Pragma("unroll")                                                 \
            for (int reg = 0; reg < 4; ++reg) {                               \
                float pv = h2f(hB[reg]);                                      \
                int k = k0 + nt * 16 + quad * 4 + reg;                        \
                if ((MODE) == 1) pv = (k == q + 1) ? 0.f : pv;                \
                if ((MODE) == 2) pv = (k >= q + 2) ? pv : 0.f;                \
                sacc[nt][reg] += pv;                                          \
            }                                                                 \
        }                                                                     \
    }

    // prologue: stage tile 0; load resident fragments
    STAGE_KV(0)

    // qv fragments (G B-operand): 5 q-tiles (rows qb..qb+79, clamped)
    v8s qvf0[5], qvf1[5];
#pragma unroll
    for (int qt2 = 0; qt2 < 5; ++qt2) {
        int r = qb + qt2 * 16 + l16;
        if (r > 2047) r = 2047;
        qvf0[qt2] = *(const v8s*)(QV + (size_t)r * DHD + quad * 8);
        qvf1[qt2] = *(const v8s*)(QV + (size_t)r * DHD + 32 + quad * 8);
    }
    const v8s bq0 = *(const v8s*)(QU + (size_t)q * DHD + quad * 8);
    const v8s bq1 = *(const v8s*)(QU + (size_t)q * DHD + 32 + quad * 8);

    float m_run = -1e30f, l_run = 0.f;
    v4f accv[4];
#pragma unroll
    for (int r = 0; r < 4; ++r) accv[r] = (v4f){0.f, 0.f, 0.f, 0.f};

    for (int tt = 0; tt < 16; ++tt) {
        const int k0 = tt * 128;
        int jb0B = k0 - qb - 65; if (jb0B < 0) jb0B = 0;
        const int jb0_1 = (tt <= t_mix) ? (1984 + k0 - qb) : jb0B;

        // issue pb-window loads early (fly under QK)
        v8s af0[3], af1[3];
        G_LOAD_AF(jb0_1)

        __syncthreads();   // stage(tt) complete & visible

        // QK^T from Kbuf (swizzled ds_read_b128); QU prescaled
        v4f sacc[8];
        __builtin_amdgcn_s_setprio(1);
#pragma unroll
        for (int nt = 0; nt < 8; ++nt) {
            int r = nt * 16 + l16;
            const unsigned short* kl = Kbuf + r * 64;
            v8s a0 = *(const v8s*)(kl + ((quad ^ (r & 7)) * 8));
            v8s a1 = *(const v8s*)(kl + (((4 + quad) ^ (r & 7)) * 8));
            v4f c = (v4f){0.f, 0.f, 0.f, 0.f};
            c = __builtin_amdgcn_mfma_f32_16x16x32_f16(a0, bq0, c, 0, 0, 0);
            c = __builtin_amdgcn_mfma_f32_16x16x32_f16(a1, bq1, c, 0, 0, 0);
            sacc[nt] = c;
        }
        __builtin_amdgcn_s_setprio(0);

        // G window 1 build + extraction (per tile class; block-uniform)
        if (tt < t_mix) {
            G_MFMA_STORE(4)
            __syncthreads();
            EXTRACT_A(0)
        } else if (tt == t_mix) {
            G_MFMA_STORE(4)
            __syncthreads();
            EXTRACT_A(1)
            __syncthreads();          // A reads done before B overwrites G
            G_LOAD_AF(jb0B)
            G_MFMA_STORE(5)
            __syncthreads();
            EXTRACT_B(2)
        } else {
            G_MFMA_STORE(5)
            __syncthreads();
            if (tt == t_mix + 1) {
                EXTRACT_B(1)
            } else {
                EXTRACT_B(0)
            }
        }

        // online softmax (inputs already scaled)
        float tm = -1e30f;
#pragma unroll
        for (int nt = 0; nt < 8; ++nt)
#pragma unroll
            for (int reg = 0; reg < 4; ++reg) tm = fmaxf(tm, sacc[nt][reg]);
        tm = fmaxf(tm, __shfl_xor(tm, 16));
        tm = fmaxf(tm, __shfl_xor(tm, 32));
        float mn = fmaxf(m_run, tm);
        float al = __expf(m_run - mn);
        float rs = 0.f;
#pragma unroll
        for (int nt = 0; nt < 8; ++nt)
#pragma unroll
            for (int reg = 0; reg < 4; ++reg) {
                sacc[nt][reg] = __expf(sacc[nt][reg] - mn);
                rs += sacc[nt][reg];
            }
        rs += __shfl_xor(rs, 16);
        rs += __shfl_xor(rs, 32);
        l_run = l_run * al + rs;
        m_run = mn;

        float alr[4];
#pragma unroll
        for (int reg = 0; reg < 4; ++reg) alr[reg] = __shfl(al, quad * 4 + reg);
#pragma unroll
        for (int ntd = 0; ntd < 4; ++ntd)
#pragma unroll
            for (int reg = 0; reg < 4; ++reg) accv[ntd][reg] *= alr[reg];

        // pack P to fp16 word-pairs
        unsigned pk[8][2];
#pragma unroll
        for (int nt = 0; nt < 8; ++nt) {
            pk[nt][0] = pkh(sacc[nt][0], sacc[nt][1]);
            pk[nt][1] = pkh(sacc[nt][2], sacc[nt][3]);
        }

        // PV: A-fragment via shfl transpose, B from Vbuf (swizzled)
        const int sA = l16 + ((quad & 1) * 32);
        const bool hi = (quad >= 2);
#pragma unroll
        for (int c4 = 0; c4 < 4; ++c4) {
            unsigned a0A = __shfl((int)pk[c4 * 2][0], sA);
            unsigned a1A = __shfl((int)pk[c4 * 2][1], sA);
            unsigned a0B = __shfl((int)pk[c4 * 2][0], sA + 16);
            unsigned a1B = __shfl((int)pk[c4 * 2][1], sA + 16);
            unsigned b0A = __shfl((int)pk[c4 * 2 + 1][0], sA);
            unsigned b1A = __shfl((int)pk[c4 * 2 + 1][1], sA);
            unsigned b0B = __shfl((int)pk[c4 * 2 + 1][0], sA + 16);
            unsigned b1B = __shfl((int)pk[c4 * 2 + 1][1], sA + 16);
            union { unsigned u[4]; v8s v; } apu;
            apu.u[0] = hi ? b0A : a0A;
            apu.u[1] = hi ? b1A : a1A;
            apu.u[2] = hi ? b0B : a0B;
            apu.u[3] = hi ? b1B : a1B;
            __builtin_amdgcn_s_setprio(1);
#pragma unroll
            for (int ntd = 0; ntd < 4; ++ntd) {
                int d = ntd * 16 + l16;
                v8s bv8 = *(const v8s*)(Vbuf + d * 128 +
                                        (((c4 * 4 + quad) ^ (d & 15)) * 8));
                accv[ntd] = __builtin_amdgcn_mfma_f32_16x16x32_f16(apu.v, bv8, accv[ntd], 0, 0, 0);
            }
            __builtin_amdgcn_s_setprio(0);
        }

        __syncthreads();   // all waves done with Kbuf/Vbuf/Gb
        if (tt < 15) STAGE_KV(tt + 1)
    }
#undef STAGE_KV
#undef G_LOAD_AF
#undef G_MFMA_STORE
#undef EXTRACT_A
#undef EXTRACT_B

    // epilogue: each wave owns its 16 q-rows completely.
    const int bb = g >> 3, h = g & 7;
    float inv[4];
#pragma unroll
    for (int reg = 0; reg < 4; ++reg)
        inv[reg] = 1.f / __shfl(l_run, quad * 4 + reg);
#pragma unroll
    for (int ntd = 0; ntd < 4; ++ntd)
#pragma unroll
        for (int reg = 0; reg < 4; ++reg) {
            int qq = q0w + quad * 4 + reg;
            ctx[((size_t)(bb * S_LEN + qq)) * DM + h * DHD + ntd * 16 + l16] =
                f2h(accv[ntd][reg] * inv[reg]);
        }
}

// ---------------------------------------------------------------------------
// out_mfma, Round-19: LDS-staged + dense LDS-bounce epilogue.
// acc[i][j][reg] = C[n = n0blk + wm*64 + i*16 + quad*4 + reg]
//                   [s = s0blk + wn*64 + j*16 + l16]
// Repack through a 64x132 fp32 half-tile (aliased onto staging) then write
// dense 512B row-chunks (out rows are 2KB; tile covers 128 n = 512B/row).
// ---------------------------------------------------------------------------
__global__ __launch_bounds__(256)
void out_mfma(const float* __restrict__ bo, const char* __restrict__ wsb,
              float* __restrict__ out)
{
    __shared__ __align__(16) unsigned char ORAW[64 * 132 * 4];   // 33.8 KB
    unsigned short* Abuf = (unsigned short*)ORAW;          // staging A (16 KB)
    unsigned short* Bbuf = (unsigned short*)ORAW + 8192;   // staging B (16 KB)
    float* TO = (float*)ORAW;                              // epilogue [64][132]

    const int t = threadIdx.x;
    const int wave = t >> 6, lane = t & 63;
    const int quad = lane >> 4, l16 = lane & 15;
    const int wm = wave >> 1, wn = wave & 1;
    const unsigned short* matA = (const unsigned short*)(wsb + BY_WT)
                                 + (size_t)4 * WT_MAT_HALFS
                                 + (size_t)(blockIdx.y * 128) * 512;
    const unsigned short* matB = (const unsigned short*)(wsb + BY_CTX)
                                 + (size_t)(blockIdx.x * 128) * 512;

    const int rowl = lane >> 3, chl = lane & 7;

#define OSTAGE(KB)                                                            \
    {                                                                         \
        _Pragma("unroll")                                                     \
        for (int jj = 0; jj < 4; ++jj) {                                      \
            const int j = wave * 4 + jj;                                      \
            const int r = j * 8 + rowl;                                       \
            const int c = chl ^ (r & 7);                                      \
            __builtin_amdgcn_global_load_lds(                                 \
                (const __attribute__((address_space(1))) unsigned int*)       \
                    (matA + (size_t)r * 512 + (KB) * 64 + c * 8),             \
                (__attribute__((address_space(3))) unsigned int*)             \
                    (Abuf + j * 512), 16, 0, 0);                              \
            __builtin_amdgcn_global_load_lds(                                 \
                (const __attribute__((address_space(1))) unsigned int*)       \
                    (matB + (size_t)r * 512 + (KB) * 64 + c * 8),             \
                (__attribute__((address_space(3))) unsigned int*)             \
                    (Bbuf + j * 512), 16, 0, 0);                              \
        }                                                                     \
    }

    v4f acc[4][4];
#pragma unroll
    for (int i = 0; i < 4; ++i)
#pragma unroll
        for (int j = 0; j < 4; ++j) acc[i][j] = (v4f){0.f, 0.f, 0.f, 0.f};

    OSTAGE(0)
    for (int kb = 0; kb < 8; ++kb) {
        __syncthreads();
        v8s af0[4], af1[4], bf0[4], bf1[4];
#pragma unroll
        for (int i = 0; i < 4; ++i) {
            int rA = wm * 64 + i * 16 + l16;
            const unsigned short* al = Abuf + rA * 64;
            af0[i] = *(const v8s*)(al + ((quad ^ (rA & 7)) * 8));
            af1[i] = *(const v8s*)(al + (((4 + quad) ^ (rA & 7)) * 8));
            int rB = wn * 64 + i * 16 + l16;
            const unsigned short* bl = Bbuf + rB * 64;
            bf0[i] = *(const v8s*)(bl + ((quad ^ (rB & 7)) * 8));
            bf1[i] = *(const v8s*)(bl + (((4 + quad) ^ (rB & 7)) * 8));
        }
#pragma unroll
        for (int i = 0; i < 4; ++i)
#pragma unroll
            for (int j = 0; j < 4; ++j) {
                acc[i][j] = __builtin_amdgcn_mfma_f32_16x16x32_f16(af0[i], bf0[j], acc[i][j], 0, 0, 0);
                acc[i][j] = __builtin_amdgcn_mfma_f32_16x16x32_f16(af1[i], bf1[j], acc[i][j], 0, 0, 0);
            }
        __syncthreads();
        if (kb < 7) OSTAGE(kb + 1)
    }
#undef OSTAGE
    // staging LDS dead after final barrier.

    const int n0blk = blockIdx.y * 128;
    const int s0blk = blockIdx.x * 128;

    for (int hs = 0; hs < 2; ++hs) {
        if (wn == hs) {
#pragma unroll
            for (int i = 0; i < 4; ++i) {
                int n_loc = wm * 64 + i * 16 + quad * 4;
#pragma unroll
                for (int j = 0; j < 4; ++j) {
                    int s_loc = j * 16 + l16;
                    *(v4f*)&TO[s_loc * 132 + n_loc] = acc[i][j];
                }
            }
        }
        __syncthreads();
        {
            const int col4 = t & 31, rowb = t >> 5;
            float4 b4 = *(const float4*)(bo + n0blk + col4 * 4);
#pragma unroll
            for (int ii = 0; ii < 8; ++ii) {
                int row = rowb + ii * 8;
                int s = s0blk + hs * 64 + row;
                const float* tr = &TO[row * 132 + col4 * 4];
                float4 v = *(const float4*)tr;
                *(float4*)(out + (size_t)s * DM + n0blk + col4 * 4) =
                    make_float4(v.x + b4.x, v.y + b4.y, v.z + b4.z, v.w + b4.w);
            }
        }
        __syncthreads();
    }
}

// Fallback when ws_size is insufficient: clean mismatch instead of OOB writes.
__global__ void zero_fill(float* __restrict__ p, int n)
{
    int i = blockIdx.x * 256 + threadIdx.x;
    if (i < n) p[i] = 0.f;
}

// ---------------------------------------------------------------------------
extern "C" void kernel_launch(void* const* d_in, const int* in_sizes, int n_in,
                              void* d_out, int out_size, void* d_ws, size_t ws_size,
                              hipStream_t stream)
{
    const float* x   = (const float*)d_in[0];
    const float* pos = (const float*)d_in[1];
    const float* Wq  = (const float*)d_in[2];
    const float* bq  = (const float*)d_in[3];
    const float* Wk  = (const float*)d_in[4];
    const float* bk  = (const float*)d_in[5];
    const float* Wv  = (const float*)d_in[6];
    const float* bv  = (const float*)d_in[7];
    const float* Wp  = (const float*)d_in[8];
    const float* u   = (const float*)d_in[9];
    const float* v   = (const float*)d_in[10];
    const float* Wo  = (const float*)d_in[11];
    const float* bo  = (const float*)d_in[12];
    char* wsb  = (char*)d_ws;
    float* out = (float*)d_out;

    // Workspace guard (no Ppos tensor anymore).
    if (ws_size < (size_t)BY_END + 1024) {
        zero_fill<<<(out_size + 255) / 256, 256, 0, stream>>>(out, out_size);
        return;
    }

    // 1. dtype prep
    conv_inputs<<<dim3(2048, 1, 2), 256, 0, stream>>>(x, pos, wsb);
    conv_wt<<<dim3(8, 8, 5), 256, 0, stream>>>(Wq, Wk, Wv, Wp, Wo, wsb);

    // 2. projections (fp16 MFMA, LDS-staged, dense epilogue; QU/QV prescaled)
    proj_mfma<<<dim3(32, 4, 4), 256, 0, stream>>>(bq, bk, bv, u, v, wsb);

    // 3. fused attention (single dispatch, all 16 batch-heads, XCD-swizzled)
    attn_fused<<<dim3(NBH * 32), 256, 0, stream>>>(
        (const unsigned short*)(wsb + BY_QU),
        (const unsigned short*)(wsb + BY_K),
        (const unsigned short*)(wsb + BY_VT),
        (const unsigned short*)(wsb + BY_QV),
        (const unsigned short*)(wsb + BY_PB),
        (unsigned short*)(wsb + BY_CTX));

    // 4. output projection (fp16 MFMA, LDS-staged, dense epilogue, fp32 out)
    out_mfma<<<dim3(32, 4), 256, 0, stream>>>(bo, wsb, out);
}